// Round 1
// baseline (3002.580 us; speedup 1.0000x reference)
//
#include <hip/hip_runtime.h>
#include <math.h>

// Problem constants
#define B_ 2
#define S_ 2048
#define D_ 2048
#define H_ 16
#define HD_ 128
#define TOPK_ 256
#define HIDDEN_ 8192
#define EPS_ 1e-6f

constexpr int ROWS_SEL = B_ * TOPK_;      // 512 selected rows (both batches)
constexpr int ROWS_ALL = ROWS_SEL + B_;   // +1 "unselected representative" row per batch

// ---------------------------------------------------------------------------
// Block reduction helpers (256 threads = 4 waves of 64)
// ---------------------------------------------------------------------------
__device__ __forceinline__ float block_sum_256(float v, float* red4) {
    for (int o = 32; o; o >>= 1) v += __shfl_down(v, o);
    if ((threadIdx.x & 63) == 0) red4[threadIdx.x >> 6] = v;
    __syncthreads();
    float t = red4[0] + red4[1] + red4[2] + red4[3];
    __syncthreads();
    return t;
}

__device__ __forceinline__ float block_max_256(float v, float* red4) {
    for (int o = 32; o; o >>= 1) v = fmaxf(v, __shfl_down(v, o));
    if ((threadIdx.x & 63) == 0) red4[threadIdx.x >> 6] = v;
    __syncthreads();
    float t = fmaxf(fmaxf(red4[0], red4[1]), fmaxf(red4[2], red4[3]));
    __syncthreads();
    return t;
}

// ---------------------------------------------------------------------------
// 1. Router: tw[b,s] = dot(x[b,s,:], router_w[:,0])
// ---------------------------------------------------------------------------
__global__ __launch_bounds__(256) void router_kernel(const float* __restrict__ x,
                                                     const float* __restrict__ rw,
                                                     float* __restrict__ tw) {
    int token = blockIdx.x;  // b*S + s
    const float* xr = x + (long)token * D_;
    float s = 0.f;
    for (int c = threadIdx.x; c < D_; c += 256) s += xr[c] * rw[c];
    __shared__ float red4[4];
    float tot = block_sum_256(s, red4);
    if (threadIdx.x == 0) tw[token] = tot;
}

// ---------------------------------------------------------------------------
// 2. Top-k per batch: bitonic sort of 2048 (value desc, index asc tie-break)
//    Writes: topk_idx as FLOATS into d_out region, sel_idx ints, sel_pos map.
// ---------------------------------------------------------------------------
__global__ __launch_bounds__(1024) void topk_kernel(const float* __restrict__ tw,
                                                    float* __restrict__ idx_out,
                                                    int* __restrict__ sel_idx,
                                                    int* __restrict__ sel_pos) {
    int b = blockIdx.x;
    __shared__ float v[S_];
    __shared__ int id[S_];
    int t = threadIdx.x;
    for (int i = t; i < S_; i += 1024) {
        v[i] = tw[b * S_ + i];
        id[i] = i;
        sel_pos[b * S_ + i] = -1;
    }
    __syncthreads();
    for (int k = 2; k <= S_; k <<= 1) {
        for (int j = k >> 1; j > 0; j >>= 1) {
            for (int i = t; i < S_; i += 1024) {
                int ixj = i ^ j;
                if (ixj > i) {
                    float va = v[i], vb = v[ixj];
                    int ia = id[i], ib = id[ixj];
                    // "before" = a precedes b in final order (desc value, asc idx)
                    bool before = (va > vb) || (va == vb && ia < ib);
                    bool dir = ((i & k) == 0);
                    if (dir != before) {
                        v[i] = vb; v[ixj] = va;
                        id[i] = ib; id[ixj] = ia;
                    }
                }
            }
            __syncthreads();
        }
    }
    if (t < TOPK_) {
        idx_out[b * TOPK_ + t] = (float)id[t];
        sel_idx[b * TOPK_ + t] = id[t];
        sel_pos[b * S_ + id[t]] = t;
    }
}

// ---------------------------------------------------------------------------
// 3. Gather selected rows of x + RMSNorm -> XN (512 x 2048)
// ---------------------------------------------------------------------------
__global__ __launch_bounds__(256) void gather_rmsnorm_kernel(const float* __restrict__ x,
                                                             const int* __restrict__ sel_idx,
                                                             const float* __restrict__ nw,
                                                             float* __restrict__ XN) {
    int r = blockIdx.x;            // 0..511
    int b = r >> 8;
    int s = sel_idx[r];
    const float* xr = x + ((long)b * S_ + s) * D_;
    __shared__ float buf[D_];
    __shared__ float red4[4];
    float ss = 0.f;
    for (int c = threadIdx.x; c < D_; c += 256) {
        float vv = xr[c];
        buf[c] = vv;
        ss += vv * vv;
    }
    float tot = block_sum_256(ss, red4);
    float scale = rsqrtf(tot / D_ + EPS_);
    for (int c = threadIdx.x; c < D_; c += 256)
        XN[(long)r * D_ + c] = buf[c] * scale * nw[c];
}

// ---------------------------------------------------------------------------
// Generic tiled f32 GEMM: C = alpha * A @ B  (B optionally transposed: (N,K))
// Batched via z: offset = (z/inner)*sXo + (z%inner)*sXi
// Requires N % 64 == 0, K % 16 == 0. M is bounds-checked.
// ---------------------------------------------------------------------------
template <bool BT>
__global__ __launch_bounds__(256) void gemm_tile(
    const float* __restrict__ A, int lda, long sAo, long sAi,
    const float* __restrict__ Bm, int ldb, long sBo, long sBi,
    float* __restrict__ C, int ldc, long sCo, long sCi,
    int M, int N, int K, int inner, float alpha) {
    constexpr int BM = 64, BN = 64, BK = 16, TM = 4, TN = 4;
    __shared__ float As[BK][BM + 1];
    __shared__ float Bs[BK][BN + 1];
    int z = blockIdx.z;
    const float* Ab = A + (long)(z / inner) * sAo + (long)(z % inner) * sAi;
    const float* Bb = Bm + (long)(z / inner) * sBo + (long)(z % inner) * sBi;
    float* Cb = C + (long)(z / inner) * sCo + (long)(z % inner) * sCi;
    int row0 = blockIdx.y * BM, col0 = blockIdx.x * BN;
    int tid = threadIdx.x;
    int tx = tid % 16, ty = tid / 16;
    float acc[TM][TN] = {};
    for (int k0 = 0; k0 < K; k0 += BK) {
        {   // load A tile (transposed into LDS): As[kk][row]
            int kk = tid & 15;
            int rb = tid >> 4;
            #pragma unroll
            for (int j = 0; j < 4; ++j) {
                int r = rb + j * 16;
                int grow = row0 + r;
                As[kk][r] = (grow < M) ? Ab[(long)grow * lda + k0 + kk] : 0.f;
            }
        }
        if (!BT) {
            int col = tid & 63;
            int kb = tid >> 6;
            #pragma unroll
            for (int j = 0; j < 4; ++j) {
                int kk = kb + j * 4;
                Bs[kk][col] = Bb[(long)(k0 + kk) * ldb + col0 + col];
            }
        } else {
            int kk = tid & 15;
            int cb = tid >> 4;
            #pragma unroll
            for (int j = 0; j < 4; ++j) {
                int col = cb + j * 16;
                Bs[kk][col] = Bb[(long)(col0 + col) * ldb + k0 + kk];
            }
        }
        __syncthreads();
        #pragma unroll
        for (int kk = 0; kk < BK; ++kk) {
            float a[TM], bb[TN];
            #pragma unroll
            for (int i = 0; i < TM; ++i) a[i] = As[kk][ty * TM + i];
            #pragma unroll
            for (int j = 0; j < TN; ++j) bb[j] = Bs[kk][tx * TN + j];
            #pragma unroll
            for (int i = 0; i < TM; ++i)
                #pragma unroll
                for (int j = 0; j < TN; ++j) acc[i][j] += a[i] * bb[j];
        }
        __syncthreads();
    }
    #pragma unroll
    for (int i = 0; i < TM; ++i) {
        int grow = row0 + ty * TM + i;
        if (grow < M) {
            #pragma unroll
            for (int j = 0; j < TN; ++j)
                Cb[(long)grow * ldc + col0 + tx * TN + j] = alpha * acc[i][j];
        }
    }
}

// ---------------------------------------------------------------------------
// 5. Rotary embedding applied in-place to Q and K (per selected row)
// ---------------------------------------------------------------------------
__global__ __launch_bounds__(256) void rotary_kernel(float* __restrict__ Q,
                                                     float* __restrict__ K,
                                                     const float* __restrict__ fc,
                                                     const int* __restrict__ sel_idx,
                                                     const int* __restrict__ sp) {
    int r = blockIdx.x;           // 0..511
    int s = sel_idx[r];
    int pos = sp[0] + s;
    const float* f = fc + (long)pos * HD_;  // 64 pairs * 2 = 128 floats / position
    float* q = Q + (long)r * D_;
    float* k = K + (long)r * D_;
    for (int p = threadIdx.x; p < (D_ / 2); p += 256) {
        int h = p >> 6, d2 = p & 63;
        int e0 = h * HD_ + d2 * 2;
        float c = f[d2 * 2], sn = f[d2 * 2 + 1];
        float q0 = q[e0], q1 = q[e0 + 1];
        q[e0] = q0 * c - q1 * sn;
        q[e0 + 1] = q0 * sn + q1 * c;
        float k0 = k[e0], k1 = k[e0 + 1];
        k[e0] = k0 * c - k1 * sn;
        k[e0 + 1] = k0 * sn + k1 * c;
    }
}

// ---------------------------------------------------------------------------
// 7. Softmax over each 256-score row (selected keys only; masked keys -> 0)
// ---------------------------------------------------------------------------
__global__ __launch_bounds__(256) void softmax_kernel(float* __restrict__ SC) {
    long row = blockIdx.x;
    float* p = SC + row * 256;
    int t = threadIdx.x;
    float v = p[t];
    __shared__ float red4[4];
    float m = block_max_256(v, red4);
    float e = expf(v - m);
    float s = block_sum_256(e, red4);
    p[t] = e / s;
}

// ---------------------------------------------------------------------------
// 9. vbar: mean of selected V rows per batch -> O rows 512+b
//    (attention output for every unselected query is exactly this)
// ---------------------------------------------------------------------------
__global__ __launch_bounds__(256) void vbar_kernel(const float* __restrict__ V,
                                                   float* __restrict__ O) {
    int b = blockIdx.y;
    int c = blockIdx.x * 256 + threadIdx.x;
    float s = 0.f;
    for (int i = 0; i < TOPK_; ++i) s += V[((long)b * TOPK_ + i) * D_ + c];
    O[(long)(ROWS_SEL + b) * D_ + c] = s * (1.f / TOPK_);
}

// ---------------------------------------------------------------------------
// 11. h = residual + attn_proj; HN = rmsnorm(h) * ffn_norm_w   (514 rows)
// ---------------------------------------------------------------------------
__global__ __launch_bounds__(256) void resid_rmsnorm_kernel(const float* __restrict__ P,
                                                            const float* __restrict__ x,
                                                            const int* __restrict__ sel_idx,
                                                            const float* __restrict__ nw,
                                                            float* __restrict__ HN) {
    int r = blockIdx.x;  // 0..513
    __shared__ float buf[D_];
    __shared__ float red4[4];
    const float* pr = P + (long)r * D_;
    const float* xr = nullptr;
    if (r < ROWS_SEL) {
        int b = r >> 8;
        int s = sel_idx[r];
        xr = x + ((long)b * S_ + s) * D_;
    }
    float ss = 0.f;
    for (int c = threadIdx.x; c < D_; c += 256) {
        float v = pr[c] + (xr ? xr[c] : 0.f);
        buf[c] = v;
        ss += v * v;
    }
    float tot = block_sum_256(ss, red4);
    float scale = rsqrtf(tot / D_ + EPS_);
    for (int c = threadIdx.x; c < D_; c += 256)
        HN[(long)r * D_ + c] = buf[c] * scale * nw[c];
}

// ---------------------------------------------------------------------------
// 13. A = silu(G1) * G3  (in place into G1)
// ---------------------------------------------------------------------------
__global__ __launch_bounds__(256) void silu_mul_kernel(float* __restrict__ G1,
                                                       const float* __restrict__ G3,
                                                       long n) {
    long i = (long)blockIdx.x * 256 + threadIdx.x;
    if (i < n) {
        float a = G1[i];
        G1[i] = (a / (1.f + expf(-a))) * G3[i];
    }
}

// ---------------------------------------------------------------------------
// 15. Scatter rows to output: selected -> their row, unselected -> batch row
// ---------------------------------------------------------------------------
__global__ __launch_bounds__(256) void scatter_kernel(const float* __restrict__ OUTR,
                                                      const int* __restrict__ sel_pos,
                                                      float* __restrict__ out) {
    int blk = blockIdx.x;      // b*S + s
    int b = blk >> 11;
    int p = sel_pos[blk];
    int row = (p >= 0) ? (b * TOPK_ + p) : (ROWS_SEL + b);
    const float* src = OUTR + (long)row * D_;
    float* dst = out + (long)blk * D_;
    for (int c = threadIdx.x; c < D_; c += 256) dst[c] = src[c];
}

// ---------------------------------------------------------------------------
extern "C" void kernel_launch(void* const* d_in, const int* in_sizes, int n_in,
                              void* d_out, int out_size, void* d_ws, size_t ws_size,
                              hipStream_t stream) {
    const float* x        = (const float*)d_in[0];
    const int*   startpos = (const int*)d_in[1];
    const float* freqs    = (const float*)d_in[2];
    const float* router_w = (const float*)d_in[3];
    const float* wq       = (const float*)d_in[4];
    const float* wk       = (const float*)d_in[5];
    const float* wv       = (const float*)d_in[6];
    const float* wo       = (const float*)d_in[7];
    const float* w1       = (const float*)d_in[8];
    const float* w2       = (const float*)d_in[9];
    const float* w3       = (const float*)d_in[10];
    const float* attn_w   = (const float*)d_in[11];
    const float* ffn_w    = (const float*)d_in[12];

    float* out     = (float*)d_out;
    float* tw_out  = out + (long)B_ * S_ * D_;   // token_weights region
    float* idx_out = tw_out + (long)B_ * S_;     // topk_idx region (as floats)

    // Workspace arena
    char* ws = (char*)d_ws;
    auto alloc = [&](size_t bytes) -> void* {
        void* p = (void*)ws;
        ws += (bytes + 255) / 256 * 256;
        return p;
    };
    int*   sel_idx = (int*)alloc((size_t)B_ * TOPK_ * sizeof(int));
    int*   sel_pos = (int*)alloc((size_t)B_ * S_ * sizeof(int));
    float* XN   = (float*)alloc((size_t)ROWS_SEL * D_ * sizeof(float));
    float* Q    = (float*)alloc((size_t)ROWS_SEL * D_ * sizeof(float));
    float* K    = (float*)alloc((size_t)ROWS_SEL * D_ * sizeof(float));
    float* V    = (float*)alloc((size_t)ROWS_SEL * D_ * sizeof(float));
    float* SC   = (float*)alloc((size_t)B_ * H_ * TOPK_ * TOPK_ * sizeof(float));
    float* O    = (float*)alloc((size_t)ROWS_ALL * D_ * sizeof(float));
    float* P    = (float*)alloc((size_t)ROWS_ALL * D_ * sizeof(float));
    float* HN   = (float*)alloc((size_t)ROWS_ALL * D_ * sizeof(float));
    float* G1   = (float*)alloc((size_t)ROWS_ALL * HIDDEN_ * sizeof(float));
    float* G3   = (float*)alloc((size_t)ROWS_ALL * HIDDEN_ * sizeof(float));
    float* OUTR = (float*)alloc((size_t)ROWS_ALL * D_ * sizeof(float));

    const float inv_sqrt_hd = 0.08838834764831845f;  // 1/sqrt(128)

    // 1. Router
    router_kernel<<<B_ * S_, 256, 0, stream>>>(x, router_w, tw_out);
    // 2. Top-k
    topk_kernel<<<B_, 1024, 0, stream>>>(tw_out, idx_out, sel_idx, sel_pos);
    // 3. Gather + RMSNorm
    gather_rmsnorm_kernel<<<ROWS_SEL, 256, 0, stream>>>(x, sel_idx, attn_w, XN);
    // 4. Q/K/V projections: (512,2048) @ (2048,2048)
    {
        dim3 g(D_ / 64, ROWS_SEL / 64, 1);
        gemm_tile<false><<<g, 256, 0, stream>>>(XN, D_, 0, 0, wq, D_, 0, 0,
                                                Q, D_, 0, 0, ROWS_SEL, D_, D_, 1, 1.f);
        gemm_tile<false><<<g, 256, 0, stream>>>(XN, D_, 0, 0, wk, D_, 0, 0,
                                                K, D_, 0, 0, ROWS_SEL, D_, D_, 1, 1.f);
        gemm_tile<false><<<g, 256, 0, stream>>>(XN, D_, 0, 0, wv, D_, 0, 0,
                                                V, D_, 0, 0, ROWS_SEL, D_, D_, 1, 1.f);
    }
    // 5. Rotary on Q, K
    rotary_kernel<<<ROWS_SEL, 256, 0, stream>>>(Q, K, freqs, sel_idx, startpos);
    // 6. Scores = Q K^T / sqrt(HD), batched over (b,h): M=256,N=256,K=128
    {
        dim3 g(TOPK_ / 64, TOPK_ / 64, B_ * H_);
        gemm_tile<true><<<g, 256, 0, stream>>>(
            Q, D_, (long)TOPK_ * D_, HD_,
            K, D_, (long)TOPK_ * D_, HD_,
            SC, TOPK_, (long)H_ * TOPK_ * TOPK_, (long)TOPK_ * TOPK_,
            TOPK_, TOPK_, HD_, H_, inv_sqrt_hd);
    }
    // 7. Softmax over each score row
    softmax_kernel<<<B_ * H_ * TOPK_, 256, 0, stream>>>(SC);
    // 8. O = P @ V, batched over (b,h): M=256,N=128,K=256
    {
        dim3 g(HD_ / 64, TOPK_ / 64, B_ * H_);
        gemm_tile<false><<<g, 256, 0, stream>>>(
            SC, TOPK_, (long)H_ * TOPK_ * TOPK_, (long)TOPK_ * TOPK_,
            V, D_, (long)TOPK_ * D_, HD_,
            O, D_, (long)TOPK_ * D_, HD_,
            TOPK_, HD_, TOPK_, H_, 1.f);
    }
    // 9. vbar rows (attention output for all unselected queries)
    {
        dim3 g(D_ / 256, B_, 1);
        vbar_kernel<<<g, 256, 0, stream>>>(V, O);
    }
    // 10. Output projection: (514,2048) @ (2048,2048)
    {
        dim3 g(D_ / 64, (ROWS_ALL + 63) / 64, 1);
        gemm_tile<false><<<g, 256, 0, stream>>>(O, D_, 0, 0, wo, D_, 0, 0,
                                                P, D_, 0, 0, ROWS_ALL, D_, D_, 1, 1.f);
    }
    // 11. Residual + RMSNorm
    resid_rmsnorm_kernel<<<ROWS_ALL, 256, 0, stream>>>(P, x, sel_idx, ffn_w, HN);
    // 12. FFN up-projections: (514,2048) @ (2048,8192)
    {
        dim3 g(HIDDEN_ / 64, (ROWS_ALL + 63) / 64, 1);
        gemm_tile<false><<<g, 256, 0, stream>>>(HN, D_, 0, 0, w1, HIDDEN_, 0, 0,
                                                G1, HIDDEN_, 0, 0, ROWS_ALL, HIDDEN_, D_, 1, 1.f);
        gemm_tile<false><<<g, 256, 0, stream>>>(HN, D_, 0, 0, w3, HIDDEN_, 0, 0,
                                                G3, HIDDEN_, 0, 0, ROWS_ALL, HIDDEN_, D_, 1, 1.f);
    }
    // 13. silu(G1) * G3
    {
        long n = (long)ROWS_ALL * HIDDEN_;
        silu_mul_kernel<<<(unsigned)((n + 255) / 256), 256, 0, stream>>>(G1, G3, n);
    }
    // 14. FFN down-projection: (514,8192) @ (8192,2048)
    {
        dim3 g(D_ / 64, (ROWS_ALL + 63) / 64, 1);
        gemm_tile<false><<<g, 256, 0, stream>>>(G1, HIDDEN_, 0, 0, w2, D_, 0, 0,
                                                OUTR, D_, 0, 0, ROWS_ALL, D_, HIDDEN_, 1, 1.f);
    }
    // 15. Scatter to output
    scatter_kernel<<<B_ * S_, 256, 0, stream>>>(OUTR, sel_pos, out);
}

// Round 2
// 775.836 us; speedup vs baseline: 3.8701x; 3.8701x over previous
//
#include <hip/hip_runtime.h>
#include <hip/hip_bf16.h>
#include <math.h>

// Problem constants
#define B_ 2
#define S_ 2048
#define D_ 2048
#define H_ 16
#define HD_ 128
#define TOPK_ 256
#define HIDDEN_ 8192
#define EPS_ 1e-6f

constexpr int ROWS_SEL = B_ * TOPK_;      // 512 selected rows (both batches)
constexpr int ROWS_ALL = ROWS_SEL + B_;   // +2 "unselected representative" rows

typedef __attribute__((ext_vector_type(8))) short bf16x8;
typedef __attribute__((ext_vector_type(4))) float f32x4;

__device__ __forceinline__ short f2bf(float f) {
    __hip_bfloat16 h = __float2bfloat16(f);
    return *reinterpret_cast<short*>(&h);
}

__device__ __forceinline__ void gll16(const void* g, void* l) {
    __builtin_amdgcn_global_load_lds(
        (const __attribute__((address_space(1))) unsigned int*)g,
        (__attribute__((address_space(3))) unsigned int*)l, 16, 0, 0);
}

// ---------------------------------------------------------------------------
// Block reduction helpers (256 threads = 4 waves of 64)
// ---------------------------------------------------------------------------
__device__ __forceinline__ float block_sum_256(float v, float* red4) {
    for (int o = 32; o; o >>= 1) v += __shfl_down(v, o);
    if ((threadIdx.x & 63) == 0) red4[threadIdx.x >> 6] = v;
    __syncthreads();
    float t = red4[0] + red4[1] + red4[2] + red4[3];
    __syncthreads();
    return t;
}

__device__ __forceinline__ float block_max_256(float v, float* red4) {
    for (int o = 32; o; o >>= 1) v = fmaxf(v, __shfl_down(v, o));
    if ((threadIdx.x & 63) == 0) red4[threadIdx.x >> 6] = v;
    __syncthreads();
    float t = fmaxf(fmaxf(red4[0], red4[1]), fmaxf(red4[2], red4[3]));
    __syncthreads();
    return t;
}

// ---------------------------------------------------------------------------
// 1. Router: tw[b,s] = dot(x[b,s,:], router_w[:,0])  -- exact f32
// ---------------------------------------------------------------------------
__global__ __launch_bounds__(256) void router_kernel(const float* __restrict__ x,
                                                     const float* __restrict__ rw,
                                                     float* __restrict__ tw) {
    int token = blockIdx.x;
    const float* xr = x + (long)token * D_;
    float s = 0.f;
    for (int c = threadIdx.x; c < D_; c += 256) s += xr[c] * rw[c];
    __shared__ float red4[4];
    float tot = block_sum_256(s, red4);
    if (threadIdx.x == 0) tw[token] = tot;
}

// ---------------------------------------------------------------------------
// 2. Top-k per batch: bitonic sort (value desc, index asc tie-break)
// ---------------------------------------------------------------------------
__global__ __launch_bounds__(1024) void topk_kernel(const float* __restrict__ tw,
                                                    float* __restrict__ idx_out,
                                                    int* __restrict__ sel_idx,
                                                    int* __restrict__ sel_pos) {
    int b = blockIdx.x;
    __shared__ float v[S_];
    __shared__ int id[S_];
    int t = threadIdx.x;
    for (int i = t; i < S_; i += 1024) {
        v[i] = tw[b * S_ + i];
        id[i] = i;
        sel_pos[b * S_ + i] = -1;
    }
    __syncthreads();
    for (int k = 2; k <= S_; k <<= 1) {
        for (int j = k >> 1; j > 0; j >>= 1) {
            for (int i = t; i < S_; i += 1024) {
                int ixj = i ^ j;
                if (ixj > i) {
                    float va = v[i], vb = v[ixj];
                    int ia = id[i], ib = id[ixj];
                    bool before = (va > vb) || (va == vb && ia < ib);
                    bool dir = ((i & k) == 0);
                    if (dir != before) {
                        v[i] = vb; v[ixj] = va;
                        id[i] = ib; id[ixj] = ia;
                    }
                }
            }
            __syncthreads();
        }
    }
    if (t < TOPK_) {
        idx_out[b * TOPK_ + t] = (float)id[t];
        sel_idx[b * TOPK_ + t] = id[t];
        sel_pos[b * S_ + id[t]] = t;
    }
}

// ---------------------------------------------------------------------------
// 3. Gather selected rows of x + RMSNorm -> XN bf16 (512 x 2048)
// ---------------------------------------------------------------------------
__global__ __launch_bounds__(256) void gather_rmsnorm_kernel(const float* __restrict__ x,
                                                             const int* __restrict__ sel_idx,
                                                             const float* __restrict__ nw,
                                                             short* __restrict__ XN) {
    int r = blockIdx.x;
    int b = r >> 8;
    int s = sel_idx[r];
    const float* xr = x + ((long)b * S_ + s) * D_;
    __shared__ float buf[D_];
    __shared__ float red4[4];
    float ss = 0.f;
    for (int c = threadIdx.x; c < D_; c += 256) {
        float vv = xr[c];
        buf[c] = vv;
        ss += vv * vv;
    }
    float tot = block_sum_256(ss, red4);
    float scale = rsqrtf(tot / D_ + EPS_);
    for (int c = threadIdx.x; c < D_; c += 256)
        XN[(long)r * D_ + c] = f2bf(buf[c] * scale * nw[c]);
}

// ---------------------------------------------------------------------------
// Weight transpose + f32->bf16: W (K,N) row-major -> WT (N,K) bf16 row-major
// ---------------------------------------------------------------------------
__global__ __launch_bounds__(256) void transpose_cvt(const float* __restrict__ W,
                                                     short* __restrict__ WT,
                                                     int K, int N) {
    __shared__ float L[64][65];
    int n0 = blockIdx.x * 64, k0 = blockIdx.y * 64;
    int t = threadIdx.x;
    int rid = t >> 4, cid = (t & 15) * 4;
    #pragma unroll
    for (int rr = 0; rr < 4; ++rr) {
        int k = rid + rr * 16;
        float4 v = *(const float4*)&W[(size_t)(k0 + k) * N + n0 + cid];
        L[k][cid] = v.x; L[k][cid + 1] = v.y; L[k][cid + 2] = v.z; L[k][cid + 3] = v.w;
    }
    __syncthreads();
    int nid = t >> 3, kc = (t & 7) * 8;
    #pragma unroll
    for (int nn = 0; nn < 2; ++nn) {
        int n = nid + nn * 32;
        union { short s[8]; int4 v; } u;
        #pragma unroll
        for (int j = 0; j < 8; ++j) u.s[j] = f2bf(L[kc + j][n]);
        *(int4*)&WT[(size_t)(n0 + n) * K + k0 + kc] = u.v;
    }
}

// ---------------------------------------------------------------------------
// MFMA bf16 GEMM (m97 recipe): C(f32, M x N) = A(bf16 M x K) @ B^T(bf16 N x K)
// 128x128 tile, BK=32, global_load_lds(16B) staging, 4 waves x (4x4) 16x16x32.
// z selects among B0/B1/B2 and offsets C by z*czStride.
// ---------------------------------------------------------------------------
__global__ __launch_bounds__(256) void gemm_mfma(
    const short* __restrict__ A,
    const short* __restrict__ B0, const short* __restrict__ B1, const short* __restrict__ B2,
    float* __restrict__ Cb, long czStride,
    int M, int N, int K) {
    __shared__ short smem[2 * 128 * 32];
    short* As = smem;              // [128][32] bf16, k-contiguous
    short* Bs = smem + 128 * 32;
    int z = blockIdx.z;
    const short* Bm = (z == 0) ? B0 : (z == 1) ? B1 : B2;
    float* C = Cb + (long)z * czStride;
    int row0 = blockIdx.y * 128, col0 = blockIdx.x * 128;
    int t = threadIdx.x;
    int lane = t & 63, w = t >> 6;
    int l16 = lane & 15, quad = lane >> 4;
    int wr = (w >> 1) * 64, wc = (w & 1) * 64;
    int rr = t >> 2, ch = (t & 3) * 8;       // staging: row rr(+64), k-chunk ch
    f32x4 acc[4][4] = {};
    for (int k0 = 0; k0 < K; k0 += 32) {
        __syncthreads();                      // LDS safe to overwrite
        #pragma unroll
        for (int rd = 0; rd < 2; ++rd) {
            int r = rr + rd * 64;
            int ar = row0 + r; ar = (ar < M) ? ar : (M - 1);
            gll16(A + (size_t)ar * K + k0 + ch, (char*)As + rd * 4096 + t * 16);
            gll16(Bm + (size_t)(col0 + r) * K + k0 + ch, (char*)Bs + rd * 4096 + t * 16);
        }
        __syncthreads();                      // vmcnt(0) drain + barrier
        bf16x8 af[4], bf[4];
        #pragma unroll
        for (int i = 0; i < 4; ++i)
            af[i] = *(const bf16x8*)(As + (wr + i * 16 + l16) * 32 + quad * 8);
        #pragma unroll
        for (int j = 0; j < 4; ++j)
            bf[j] = *(const bf16x8*)(Bs + (wc + j * 16 + l16) * 32 + quad * 8);
        #pragma unroll
        for (int i = 0; i < 4; ++i)
            #pragma unroll
            for (int j = 0; j < 4; ++j)
                acc[i][j] = __builtin_amdgcn_mfma_f32_16x16x32_bf16(af[i], bf[j], acc[i][j], 0, 0, 0);
    }
    #pragma unroll
    for (int i = 0; i < 4; ++i) {
        #pragma unroll
        for (int r = 0; r < 4; ++r) {
            int row = row0 + wr + i * 16 + quad * 4 + r;
            if (row < M) {
                #pragma unroll
                for (int j = 0; j < 4; ++j)
                    C[(size_t)row * N + col0 + wc + j * 16 + l16] = acc[i][j][r];
            }
        }
    }
}

// ---------------------------------------------------------------------------
// Generic tiled f32 GEMM (kept for small attention GEMMs)
// ---------------------------------------------------------------------------
template <bool BT>
__global__ __launch_bounds__(256) void gemm_tile(
    const float* __restrict__ A, int lda, long sAo, long sAi,
    const float* __restrict__ Bm, int ldb, long sBo, long sBi,
    float* __restrict__ C, int ldc, long sCo, long sCi,
    int M, int N, int K, int inner, float alpha) {
    constexpr int BM = 64, BN = 64, BK = 16, TM = 4, TN = 4;
    __shared__ float As[BK][BM + 1];
    __shared__ float Bs[BK][BN + 1];
    int z = blockIdx.z;
    const float* Ab = A + (long)(z / inner) * sAo + (long)(z % inner) * sAi;
    const float* Bb = Bm + (long)(z / inner) * sBo + (long)(z % inner) * sBi;
    float* Cb = C + (long)(z / inner) * sCo + (long)(z % inner) * sCi;
    int row0 = blockIdx.y * BM, col0 = blockIdx.x * BN;
    int tid = threadIdx.x;
    int tx = tid % 16, ty = tid / 16;
    float acc[TM][TN] = {};
    for (int k0 = 0; k0 < K; k0 += BK) {
        {
            int kk = tid & 15;
            int rb = tid >> 4;
            #pragma unroll
            for (int j = 0; j < 4; ++j) {
                int r = rb + j * 16;
                int grow = row0 + r;
                As[kk][r] = (grow < M) ? Ab[(long)grow * lda + k0 + kk] : 0.f;
            }
        }
        if (!BT) {
            int col = tid & 63;
            int kb = tid >> 6;
            #pragma unroll
            for (int j = 0; j < 4; ++j) {
                int kk = kb + j * 4;
                Bs[kk][col] = Bb[(long)(k0 + kk) * ldb + col0 + col];
            }
        } else {
            int kk = tid & 15;
            int cb = tid >> 4;
            #pragma unroll
            for (int j = 0; j < 4; ++j) {
                int col = cb + j * 16;
                Bs[kk][col] = Bb[(long)(col0 + col) * ldb + k0 + kk];
            }
        }
        __syncthreads();
        #pragma unroll
        for (int kk = 0; kk < BK; ++kk) {
            float a[TM], bb[TN];
            #pragma unroll
            for (int i = 0; i < TM; ++i) a[i] = As[kk][ty * TM + i];
            #pragma unroll
            for (int j = 0; j < TN; ++j) bb[j] = Bs[kk][tx * TN + j];
            #pragma unroll
            for (int i = 0; i < TM; ++i)
                #pragma unroll
                for (int j = 0; j < TN; ++j) acc[i][j] += a[i] * bb[j];
        }
        __syncthreads();
    }
    #pragma unroll
    for (int i = 0; i < TM; ++i) {
        int grow = row0 + ty * TM + i;
        if (grow < M) {
            #pragma unroll
            for (int j = 0; j < TN; ++j)
                Cb[(long)grow * ldc + col0 + tx * TN + j] = alpha * acc[i][j];
        }
    }
}

// ---------------------------------------------------------------------------
// Rotary embedding in-place on Q and K (f32)
// ---------------------------------------------------------------------------
__global__ __launch_bounds__(256) void rotary_kernel(float* __restrict__ Q,
                                                     float* __restrict__ K,
                                                     const float* __restrict__ fc,
                                                     const int* __restrict__ sel_idx,
                                                     const int* __restrict__ sp) {
    int r = blockIdx.x;
    int s = sel_idx[r];
    int pos = sp[0] + s;
    const float* f = fc + (long)pos * HD_;
    float* q = Q + (long)r * D_;
    float* k = K + (long)r * D_;
    for (int p = threadIdx.x; p < (D_ / 2); p += 256) {
        int h = p >> 6, d2 = p & 63;
        int e0 = h * HD_ + d2 * 2;
        float c = f[d2 * 2], sn = f[d2 * 2 + 1];
        float q0 = q[e0], q1 = q[e0 + 1];
        q[e0] = q0 * c - q1 * sn;
        q[e0 + 1] = q0 * sn + q1 * c;
        float k0 = k[e0], k1 = k[e0 + 1];
        k[e0] = k0 * c - k1 * sn;
        k[e0 + 1] = k0 * sn + k1 * c;
    }
}

// ---------------------------------------------------------------------------
// Softmax over each 256-score row
// ---------------------------------------------------------------------------
__global__ __launch_bounds__(256) void softmax_kernel(float* __restrict__ SC) {
    long row = blockIdx.x;
    float* p = SC + row * 256;
    int t = threadIdx.x;
    float v = p[t];
    __shared__ float red4[4];
    float m = block_max_256(v, red4);
    float e = expf(v - m);
    float s = block_sum_256(e, red4);
    p[t] = e / s;
}

// ---------------------------------------------------------------------------
// vbar: mean of selected V rows per batch -> O rows 512+b
// ---------------------------------------------------------------------------
__global__ __launch_bounds__(256) void vbar_kernel(const float* __restrict__ V,
                                                   float* __restrict__ O) {
    int b = blockIdx.y;
    int c = blockIdx.x * 256 + threadIdx.x;
    float s = 0.f;
    for (int i = 0; i < TOPK_; ++i) s += V[((long)b * TOPK_ + i) * D_ + c];
    O[(long)(ROWS_SEL + b) * D_ + c] = s * (1.f / TOPK_);
}

// ---------------------------------------------------------------------------
// f32 -> bf16 convert (vectorized by 4)
// ---------------------------------------------------------------------------
__global__ __launch_bounds__(256) void cvt_bf16_kernel(const float* __restrict__ in,
                                                       short* __restrict__ out, long n4) {
    long i = (long)blockIdx.x * 256 + threadIdx.x;
    if (i < n4) {
        float4 v = ((const float4*)in)[i];
        union { short s[4]; short4 v4; } u;
        u.s[0] = f2bf(v.x); u.s[1] = f2bf(v.y); u.s[2] = f2bf(v.z); u.s[3] = f2bf(v.w);
        ((short4*)out)[i] = u.v4;
    }
}

// ---------------------------------------------------------------------------
// h = residual + attn_proj; HN = bf16(rmsnorm(h) * ffn_norm_w)
// ---------------------------------------------------------------------------
__global__ __launch_bounds__(256) void resid_rmsnorm_kernel(const float* __restrict__ P,
                                                            const float* __restrict__ x,
                                                            const int* __restrict__ sel_idx,
                                                            const float* __restrict__ nw,
                                                            short* __restrict__ HN) {
    int r = blockIdx.x;
    __shared__ float buf[D_];
    __shared__ float red4[4];
    const float* pr = P + (long)r * D_;
    const float* xr = nullptr;
    if (r < ROWS_SEL) {
        int b = r >> 8;
        int s = sel_idx[r];
        xr = x + ((long)b * S_ + s) * D_;
    }
    float ss = 0.f;
    for (int c = threadIdx.x; c < D_; c += 256) {
        float v = pr[c] + (xr ? xr[c] : 0.f);
        buf[c] = v;
        ss += v * v;
    }
    float tot = block_sum_256(ss, red4);
    float scale = rsqrtf(tot / D_ + EPS_);
    for (int c = threadIdx.x; c < D_; c += 256)
        HN[(long)r * D_ + c] = f2bf(buf[c] * scale * nw[c]);
}

// ---------------------------------------------------------------------------
// FF = bf16(silu(G1) * G3)
// ---------------------------------------------------------------------------
__global__ __launch_bounds__(256) void silu_mul_kernel(const float* __restrict__ G1,
                                                       const float* __restrict__ G3,
                                                       short* __restrict__ FF, long n) {
    long i = (long)blockIdx.x * 256 + threadIdx.x;
    if (i < n) {
        float a = G1[i];
        FF[i] = f2bf((a / (1.f + expf(-a))) * G3[i]);
    }
}

// ---------------------------------------------------------------------------
// Scatter rows to output
// ---------------------------------------------------------------------------
__global__ __launch_bounds__(256) void scatter_kernel(const float* __restrict__ OUTR,
                                                      const int* __restrict__ sel_pos,
                                                      float* __restrict__ out) {
    int blk = blockIdx.x;
    int b = blk >> 11;
    int p = sel_pos[blk];
    int row = (p >= 0) ? (b * TOPK_ + p) : (ROWS_SEL + b);
    const float* src = OUTR + (long)row * D_;
    float* dst = out + (long)blk * D_;
    for (int c = threadIdx.x; c < D_; c += 256) dst[c] = src[c];
}

// ---------------------------------------------------------------------------
extern "C" void kernel_launch(void* const* d_in, const int* in_sizes, int n_in,
                              void* d_out, int out_size, void* d_ws, size_t ws_size,
                              hipStream_t stream) {
    const float* x        = (const float*)d_in[0];
    const int*   startpos = (const int*)d_in[1];
    const float* freqs    = (const float*)d_in[2];
    const float* router_w = (const float*)d_in[3];
    const float* wq       = (const float*)d_in[4];
    const float* wk       = (const float*)d_in[5];
    const float* wv       = (const float*)d_in[6];
    const float* wo       = (const float*)d_in[7];
    const float* w1       = (const float*)d_in[8];
    const float* w2       = (const float*)d_in[9];
    const float* w3       = (const float*)d_in[10];
    const float* attn_w   = (const float*)d_in[11];
    const float* ffn_w    = (const float*)d_in[12];

    float* out     = (float*)d_out;
    float* tw_out  = out + (long)B_ * S_ * D_;
    float* idx_out = tw_out + (long)B_ * S_;

    char* ws = (char*)d_ws;
    auto alloc = [&](size_t bytes) -> void* {
        void* p = (void*)ws;
        ws += (bytes + 255) / 256 * 256;
        return p;
    };
    int*   sel_idx = (int*)alloc((size_t)B_ * TOPK_ * sizeof(int));
    int*   sel_pos = (int*)alloc((size_t)B_ * S_ * sizeof(int));
    short* XNbf = (short*)alloc((size_t)ROWS_SEL * D_ * sizeof(short));
    float* QKV  = (float*)alloc((size_t)3 * ROWS_SEL * D_ * sizeof(float));
    float* Qf = QKV;
    float* Kf = QKV + (size_t)ROWS_SEL * D_;
    float* Vf = QKV + (size_t)2 * ROWS_SEL * D_;
    float* SC   = (float*)alloc((size_t)B_ * H_ * TOPK_ * TOPK_ * sizeof(float));
    float* O    = (float*)alloc((size_t)ROWS_ALL * D_ * sizeof(float));
    short* Obf  = (short*)alloc((size_t)ROWS_ALL * D_ * sizeof(short));
    float* P    = (float*)alloc((size_t)ROWS_ALL * D_ * sizeof(float));
    short* HNbf = (short*)alloc((size_t)ROWS_ALL * D_ * sizeof(short));
    float* G    = (float*)alloc((size_t)2 * ROWS_ALL * HIDDEN_ * sizeof(float));
    float* G1 = G;
    float* G3 = G + (size_t)ROWS_ALL * HIDDEN_;
    short* FFbf = (short*)alloc((size_t)ROWS_ALL * HIDDEN_ * sizeof(short));
    float* OUTR = (float*)alloc((size_t)ROWS_ALL * D_ * sizeof(float));
    short* WT   = (short*)alloc((size_t)2 * D_ * HIDDEN_ * sizeof(short));  // 64 MB arena
    const size_t W4M = (size_t)D_ * D_;          // 2048*2048 elements
    const size_t W16M = (size_t)D_ * HIDDEN_;    // 2048*8192 elements

    const float inv_sqrt_hd = 0.08838834764831845f;

    // 1. Router (exact f32)
    router_kernel<<<B_ * S_, 256, 0, stream>>>(x, router_w, tw_out);
    // 2. Top-k
    topk_kernel<<<B_, 1024, 0, stream>>>(tw_out, idx_out, sel_idx, sel_pos);
    // 3. Gather + RMSNorm -> bf16
    gather_rmsnorm_kernel<<<ROWS_SEL, 256, 0, stream>>>(x, sel_idx, attn_w, XNbf);
    // 4. Transpose wq/wk/wv -> bf16 (N,K); fused QKV MFMA GEMM (z=0,1,2)
    {
        dim3 tg(D_ / 64, D_ / 64);
        transpose_cvt<<<tg, 256, 0, stream>>>(wq, WT, D_, D_);
        transpose_cvt<<<tg, 256, 0, stream>>>(wk, WT + W4M, D_, D_);
        transpose_cvt<<<tg, 256, 0, stream>>>(wv, WT + 2 * W4M, D_, D_);
        dim3 g(D_ / 128, ROWS_SEL / 128, 3);
        gemm_mfma<<<g, 256, 0, stream>>>(XNbf, WT, WT + W4M, WT + 2 * W4M,
                                         QKV, (long)ROWS_SEL * D_, ROWS_SEL, D_, D_);
    }
    // 5. Rotary
    rotary_kernel<<<ROWS_SEL, 256, 0, stream>>>(Qf, Kf, freqs, sel_idx, startpos);
    // 6. Scores = Q K^T / sqrt(HD)
    {
        dim3 g(TOPK_ / 64, TOPK_ / 64, B_ * H_);
        gemm_tile<true><<<g, 256, 0, stream>>>(
            Qf, D_, (long)TOPK_ * D_, HD_,
            Kf, D_, (long)TOPK_ * D_, HD_,
            SC, TOPK_, (long)H_ * TOPK_ * TOPK_, (long)TOPK_ * TOPK_,
            TOPK_, TOPK_, HD_, H_, inv_sqrt_hd);
    }
    // 7. Softmax
    softmax_kernel<<<B_ * H_ * TOPK_, 256, 0, stream>>>(SC);
    // 8. O = P @ V
    {
        dim3 g(HD_ / 64, TOPK_ / 64, B_ * H_);
        gemm_tile<false><<<g, 256, 0, stream>>>(
            SC, TOPK_, (long)H_ * TOPK_ * TOPK_, (long)TOPK_ * TOPK_,
            Vf, D_, (long)TOPK_ * D_, HD_,
            O, D_, (long)TOPK_ * D_, HD_,
            TOPK_, HD_, TOPK_, H_, 1.f);
    }
    // 9. vbar rows
    {
        dim3 g(D_ / 256, B_, 1);
        vbar_kernel<<<g, 256, 0, stream>>>(Vf, O);
    }
    // 10. O -> bf16; wo projection (MFMA)
    {
        long n4 = (long)ROWS_ALL * D_ / 4;
        cvt_bf16_kernel<<<(unsigned)((n4 + 255) / 256), 256, 0, stream>>>(O, Obf, n4);
        dim3 tg(D_ / 64, D_ / 64);
        transpose_cvt<<<tg, 256, 0, stream>>>(wo, WT, D_, D_);
        dim3 g(D_ / 128, (ROWS_ALL + 127) / 128, 1);
        gemm_mfma<<<g, 256, 0, stream>>>(Obf, WT, WT, WT, P, 0, ROWS_ALL, D_, D_);
    }
    // 11. Residual + RMSNorm -> bf16
    resid_rmsnorm_kernel<<<ROWS_ALL, 256, 0, stream>>>(P, x, sel_idx, ffn_w, HNbf);
    // 12. w1/w3 up-projections (fused z=0,1)
    {
        dim3 tg(HIDDEN_ / 64, D_ / 64);
        transpose_cvt<<<tg, 256, 0, stream>>>(w1, WT, D_, HIDDEN_);
        transpose_cvt<<<tg, 256, 0, stream>>>(w3, WT + W16M, D_, HIDDEN_);
        dim3 g(HIDDEN_ / 128, (ROWS_ALL + 127) / 128, 2);
        gemm_mfma<<<g, 256, 0, stream>>>(HNbf, WT, WT + W16M, WT,
                                         G, (long)ROWS_ALL * HIDDEN_, ROWS_ALL, HIDDEN_, D_);
    }
    // 13. FF = bf16(silu(G1)*G3)
    {
        long n = (long)ROWS_ALL * HIDDEN_;
        silu_mul_kernel<<<(unsigned)((n + 255) / 256), 256, 0, stream>>>(G1, G3, FFbf, n);
    }
    // 14. w2 down-projection (MFMA, K=8192)
    {
        dim3 tg(D_ / 64, HIDDEN_ / 64);
        transpose_cvt<<<tg, 256, 0, stream>>>(w2, WT, HIDDEN_, D_);
        dim3 g(D_ / 128, (ROWS_ALL + 127) / 128, 1);
        gemm_mfma<<<g, 256, 0, stream>>>(FFbf, WT, WT, WT, OUTR, 0, ROWS_ALL, D_, HIDDEN_);
    }
    // 15. Scatter
    scatter_kernel<<<B_ * S_, 256, 0, stream>>>(OUTR, sel_pos, out);
}

// Round 3
// 640.341 us; speedup vs baseline: 4.6890x; 1.2116x over previous
//
#include <hip/hip_runtime.h>
#include <hip/hip_bf16.h>
#include <math.h>

// Problem constants
#define B_ 2
#define S_ 2048
#define D_ 2048
#define H_ 16
#define HD_ 128
#define TOPK_ 256
#define HIDDEN_ 8192
#define EPS_ 1e-6f

constexpr int ROWS_SEL = B_ * TOPK_;      // 512 selected rows (both batches)
constexpr int ROWS_ALL = ROWS_SEL + B_;   // +2 "unselected representative" rows

typedef __attribute__((ext_vector_type(8))) short bf16x8;
typedef __attribute__((ext_vector_type(4))) float f32x4;

__device__ __forceinline__ short f2bf(float f) {
    __hip_bfloat16 h = __float2bfloat16(f);
    return *reinterpret_cast<short*>(&h);
}

__device__ __forceinline__ void gll16(const void* g, void* l) {
    __builtin_amdgcn_global_load_lds(
        (const __attribute__((address_space(1))) unsigned int*)g,
        (__attribute__((address_space(3))) unsigned int*)l, 16, 0, 0);
}

// ---------------------------------------------------------------------------
// Block reduction helpers
// ---------------------------------------------------------------------------
__device__ __forceinline__ float block_sum_256(float v, float* red4) {
    for (int o = 32; o; o >>= 1) v += __shfl_down(v, o);
    if ((threadIdx.x & 63) == 0) red4[threadIdx.x >> 6] = v;
    __syncthreads();
    float t = red4[0] + red4[1] + red4[2] + red4[3];
    __syncthreads();
    return t;
}

__device__ __forceinline__ float block_max_256(float v, float* red4) {
    for (int o = 32; o; o >>= 1) v = fmaxf(v, __shfl_down(v, o));
    if ((threadIdx.x & 63) == 0) red4[threadIdx.x >> 6] = v;
    __syncthreads();
    float t = fmaxf(fmaxf(red4[0], red4[1]), fmaxf(red4[2], red4[3]));
    __syncthreads();
    return t;
}

// ---------------------------------------------------------------------------
// 1. Router (exact f32)
// ---------------------------------------------------------------------------
__global__ __launch_bounds__(256) void router_kernel(const float* __restrict__ x,
                                                     const float* __restrict__ rw,
                                                     float* __restrict__ tw) {
    int token = blockIdx.x;
    const float* xr = x + (long)token * D_;
    float s = 0.f;
    for (int c = threadIdx.x; c < D_; c += 256) s += xr[c] * rw[c];
    __shared__ float red4[4];
    float tot = block_sum_256(s, red4);
    if (threadIdx.x == 0) tw[token] = tot;
}

// ---------------------------------------------------------------------------
// 2. Top-k per batch (bitonic, value desc / index asc)
// ---------------------------------------------------------------------------
__global__ __launch_bounds__(1024) void topk_kernel(const float* __restrict__ tw,
                                                    float* __restrict__ idx_out,
                                                    int* __restrict__ sel_idx,
                                                    int* __restrict__ sel_pos) {
    int b = blockIdx.x;
    __shared__ float v[S_];
    __shared__ int id[S_];
    int t = threadIdx.x;
    for (int i = t; i < S_; i += 1024) {
        v[i] = tw[b * S_ + i];
        id[i] = i;
        sel_pos[b * S_ + i] = -1;
    }
    __syncthreads();
    for (int k = 2; k <= S_; k <<= 1) {
        for (int j = k >> 1; j > 0; j >>= 1) {
            for (int i = t; i < S_; i += 1024) {
                int ixj = i ^ j;
                if (ixj > i) {
                    float va = v[i], vb = v[ixj];
                    int ia = id[i], ib = id[ixj];
                    bool before = (va > vb) || (va == vb && ia < ib);
                    bool dir = ((i & k) == 0);
                    if (dir != before) {
                        v[i] = vb; v[ixj] = va;
                        id[i] = ib; id[ixj] = ia;
                    }
                }
            }
            __syncthreads();
        }
    }
    if (t < TOPK_) {
        idx_out[b * TOPK_ + t] = (float)id[t];
        sel_idx[b * TOPK_ + t] = id[t];
        sel_pos[b * S_ + id[t]] = t;
    }
}

// ---------------------------------------------------------------------------
// 3. Gather + RMSNorm -> bf16
// ---------------------------------------------------------------------------
__global__ __launch_bounds__(256) void gather_rmsnorm_kernel(const float* __restrict__ x,
                                                             const int* __restrict__ sel_idx,
                                                             const float* __restrict__ nw,
                                                             short* __restrict__ XN) {
    int r = blockIdx.x;
    int b = r >> 8;
    int s = sel_idx[r];
    const float* xr = x + ((long)b * S_ + s) * D_;
    __shared__ float buf[D_];
    __shared__ float red4[4];
    float ss = 0.f;
    for (int c = threadIdx.x; c < D_; c += 256) {
        float vv = xr[c];
        buf[c] = vv;
        ss += vv * vv;
    }
    float tot = block_sum_256(ss, red4);
    float scale = rsqrtf(tot / D_ + EPS_);
    for (int c = threadIdx.x; c < D_; c += 256)
        XN[(long)r * D_ + c] = f2bf(buf[c] * scale * nw[c]);
}

// ---------------------------------------------------------------------------
// Fused transpose+cvt of ALL 7 weights in one launch.
// W (K,N) f32 row-major -> WT (N,K) bf16 row-major.
// ---------------------------------------------------------------------------
struct TransParams {
    const float* src[7];
    short* dst[7];
    int K[7];
    int N[7];
    int pref[8];   // prefix sums of tile counts
};

__global__ __launch_bounds__(256) void transpose_all(TransParams tp) {
    int bid = blockIdx.x;
    int w = 0;
    while (bid >= tp.pref[w + 1]) ++w;
    int local = bid - tp.pref[w];
    const float* W = tp.src[w];
    short* WT = tp.dst[w];
    int K = tp.K[w], N = tp.N[w];
    int ntiles = N >> 6;
    int n0 = (local % ntiles) * 64, k0 = (local / ntiles) * 64;

    __shared__ float L[64][65];
    int t = threadIdx.x;
    int rid = t >> 4, cid = (t & 15) * 4;
    #pragma unroll
    for (int rr = 0; rr < 4; ++rr) {
        int k = rid + rr * 16;
        float4 v = *(const float4*)&W[(size_t)(k0 + k) * N + n0 + cid];
        L[k][cid] = v.x; L[k][cid + 1] = v.y; L[k][cid + 2] = v.z; L[k][cid + 3] = v.w;
    }
    __syncthreads();
    int nid = t >> 3, kc = (t & 7) * 8;
    #pragma unroll
    for (int nn = 0; nn < 2; ++nn) {
        int n = nid + nn * 32;
        union { short s[8]; int4 v; } u;
        #pragma unroll
        for (int j = 0; j < 8; ++j) u.s[j] = f2bf(L[kc + j][n]);
        *(int4*)&WT[(size_t)(n0 + n) * K + k0 + kc] = u.v;
    }
}

// ---------------------------------------------------------------------------
// MFMA bf16 GEMM with split-K.
// C(f32) = A(bf16 MxK) @ B^T(bf16 NxK); grid.z = zmat*splits + sp.
// Block computes k range [sp*K_per, (sp+1)*K_per), writes partial to
// Cb + zmat*czStride + sp*spStride (row-major MxN).
// ---------------------------------------------------------------------------
__global__ __launch_bounds__(256) void gemm_mfma(
    const short* __restrict__ A,
    const short* __restrict__ B0, const short* __restrict__ B1, const short* __restrict__ B2,
    float* __restrict__ Cb, long czStride, long spStride,
    int M, int N, int Ktot, int K_per, int splits) {
    __shared__ short smem[2 * 128 * 32];
    short* As = smem;
    short* Bs = smem + 128 * 32;
    int z = blockIdx.z;
    int zmat = z / splits, sp = z % splits;
    const short* Bm = (zmat == 0) ? B0 : (zmat == 1) ? B1 : B2;
    float* C = Cb + (long)zmat * czStride + (long)sp * spStride;
    int kbase = sp * K_per;
    int row0 = blockIdx.y * 128, col0 = blockIdx.x * 128;
    int t = threadIdx.x;
    int lane = t & 63, w = t >> 6;
    int l16 = lane & 15, quad = lane >> 4;
    int wr = (w >> 1) * 64, wc = (w & 1) * 64;
    int rr = t >> 2, ch = (t & 3) * 8;
    f32x4 acc[4][4] = {};
    for (int k0 = kbase; k0 < kbase + K_per; k0 += 32) {
        __syncthreads();
        #pragma unroll
        for (int rd = 0; rd < 2; ++rd) {
            int r = rr + rd * 64;
            int ar = row0 + r; ar = (ar < M) ? ar : (M - 1);
            gll16(A + (size_t)ar * Ktot + k0 + ch, (char*)As + rd * 4096 + t * 16);
            gll16(Bm + (size_t)(col0 + r) * Ktot + k0 + ch, (char*)Bs + rd * 4096 + t * 16);
        }
        __syncthreads();
        bf16x8 af[4], bf[4];
        #pragma unroll
        for (int i = 0; i < 4; ++i)
            af[i] = *(const bf16x8*)(As + (wr + i * 16 + l16) * 32 + quad * 8);
        #pragma unroll
        for (int j = 0; j < 4; ++j)
            bf[j] = *(const bf16x8*)(Bs + (wc + j * 16 + l16) * 32 + quad * 8);
        #pragma unroll
        for (int i = 0; i < 4; ++i)
            #pragma unroll
            for (int j = 0; j < 4; ++j)
                acc[i][j] = __builtin_amdgcn_mfma_f32_16x16x32_bf16(af[i], bf[j], acc[i][j], 0, 0, 0);
    }
    #pragma unroll
    for (int i = 0; i < 4; ++i) {
        #pragma unroll
        for (int r = 0; r < 4; ++r) {
            int row = row0 + wr + i * 16 + quad * 4 + r;
            if (row < M) {
                #pragma unroll
                for (int j = 0; j < 4; ++j)
                    C[(size_t)row * N + col0 + wc + j * 16 + l16] = acc[i][j][r];
            }
        }
    }
}

// ---------------------------------------------------------------------------
// Generic tiled f32 GEMM (attention); optional bf16 output.
// ---------------------------------------------------------------------------
template <bool BT, bool OBF>
__global__ __launch_bounds__(256) void gemm_tile(
    const float* __restrict__ A, int lda, long sAo, long sAi,
    const float* __restrict__ Bm, int ldb, long sBo, long sBi,
    void* __restrict__ Cv, int ldc, long sCo, long sCi,
    int M, int N, int K, int inner, float alpha) {
    constexpr int BM = 64, BN = 64, BK = 16, TM = 4, TN = 4;
    __shared__ float As[BK][BM + 1];
    __shared__ float Bs[BK][BN + 1];
    int z = blockIdx.z;
    const float* Ab = A + (long)(z / inner) * sAo + (long)(z % inner) * sAi;
    const float* Bb = Bm + (long)(z / inner) * sBo + (long)(z % inner) * sBi;
    long cbase = (long)(z / inner) * sCo + (long)(z % inner) * sCi;
    int row0 = blockIdx.y * BM, col0 = blockIdx.x * BN;
    int tid = threadIdx.x;
    int tx = tid % 16, ty = tid / 16;
    float acc[TM][TN] = {};
    for (int k0 = 0; k0 < K; k0 += BK) {
        {
            int kk = tid & 15;
            int rb = tid >> 4;
            #pragma unroll
            for (int j = 0; j < 4; ++j) {
                int r = rb + j * 16;
                int grow = row0 + r;
                As[kk][r] = (grow < M) ? Ab[(long)grow * lda + k0 + kk] : 0.f;
            }
        }
        if (!BT) {
            int col = tid & 63;
            int kb = tid >> 6;
            #pragma unroll
            for (int j = 0; j < 4; ++j) {
                int kk = kb + j * 4;
                Bs[kk][col] = Bb[(long)(k0 + kk) * ldb + col0 + col];
            }
        } else {
            int kk = tid & 15;
            int cb = tid >> 4;
            #pragma unroll
            for (int j = 0; j < 4; ++j) {
                int col = cb + j * 16;
                Bs[kk][col] = Bb[(long)(col0 + col) * ldb + k0 + kk];
            }
        }
        __syncthreads();
        #pragma unroll
        for (int kk = 0; kk < BK; ++kk) {
            float a[TM], bb[TN];
            #pragma unroll
            for (int i = 0; i < TM; ++i) a[i] = As[kk][ty * TM + i];
            #pragma unroll
            for (int j = 0; j < TN; ++j) bb[j] = Bs[kk][tx * TN + j];
            #pragma unroll
            for (int i = 0; i < TM; ++i)
                #pragma unroll
                for (int j = 0; j < TN; ++j) acc[i][j] += a[i] * bb[j];
        }
        __syncthreads();
    }
    #pragma unroll
    for (int i = 0; i < TM; ++i) {
        int grow = row0 + ty * TM + i;
        if (grow < M) {
            #pragma unroll
            for (int j = 0; j < TN; ++j) {
                long idx = cbase + (long)grow * ldc + col0 + tx * TN + j;
                if (OBF) ((short*)Cv)[idx] = f2bf(alpha * acc[i][j]);
                else     ((float*)Cv)[idx] = alpha * acc[i][j];
            }
        }
    }
}

// ---------------------------------------------------------------------------
// QKV finish: reduce split-K partials + rotary(Q,K) -> Qf,Kf,Vf (f32)
// Cp layout: [sp][mat(q,k,v)][512][2048]
// ---------------------------------------------------------------------------
__global__ __launch_bounds__(256) void qkv_finish(
    const float* __restrict__ Cp, const float* __restrict__ fc,
    const int* __restrict__ sel_idx, const int* __restrict__ sp0,
    float* __restrict__ Qf, float* __restrict__ Kf, float* __restrict__ Vf,
    int splits) {
    int r = blockIdx.x;
    int s = sel_idx[r];
    int pos = sp0[0] + s;
    const float* f = fc + (long)pos * HD_;
    const long matS = (long)ROWS_SEL * D_;
    const long spS = 3 * matS;
    const float* qp = Cp + (long)r * D_;
    const float* kp = qp + matS;
    const float* vp = qp + 2 * matS;
    for (int p = threadIdx.x; p < (D_ / 2); p += 256) {
        int h = p >> 6, d2 = p & 63;
        int e0 = h * HD_ + d2 * 2;
        float q0 = 0.f, q1 = 0.f, k0 = 0.f, k1 = 0.f, v0 = 0.f, v1 = 0.f;
        for (int sp = 0; sp < splits; ++sp) {
            long off = (long)sp * spS;
            q0 += qp[off + e0]; q1 += qp[off + e0 + 1];
            k0 += kp[off + e0]; k1 += kp[off + e0 + 1];
            v0 += vp[off + e0]; v1 += vp[off + e0 + 1];
        }
        float c = f[d2 * 2], sn = f[d2 * 2 + 1];
        Qf[(long)r * D_ + e0]     = q0 * c - q1 * sn;
        Qf[(long)r * D_ + e0 + 1] = q0 * sn + q1 * c;
        Kf[(long)r * D_ + e0]     = k0 * c - k1 * sn;
        Kf[(long)r * D_ + e0 + 1] = k0 * sn + k1 * c;
        Vf[(long)r * D_ + e0]     = v0;
        Vf[(long)r * D_ + e0 + 1] = v1;
    }
}

// ---------------------------------------------------------------------------
// Softmax over each 256-score row
// ---------------------------------------------------------------------------
__global__ __launch_bounds__(256) void softmax_kernel(float* __restrict__ SC) {
    long row = blockIdx.x;
    float* p = SC + row * 256;
    int t = threadIdx.x;
    float v = p[t];
    __shared__ float red4[4];
    float m = block_max_256(v, red4);
    float e = expf(v - m);
    float s = block_sum_256(e, red4);
    p[t] = e / s;
}

// ---------------------------------------------------------------------------
// vbar: mean of selected V rows per batch -> Obf rows 512+b (bf16)
// ---------------------------------------------------------------------------
__global__ __launch_bounds__(256) void vbar_kernel(const float* __restrict__ V,
                                                   short* __restrict__ Obf) {
    int b = blockIdx.y;
    int c = blockIdx.x * 256 + threadIdx.x;
    float s = 0.f;
    for (int i = 0; i < TOPK_; ++i) s += V[((long)b * TOPK_ + i) * D_ + c];
    Obf[(long)(ROWS_SEL + b) * D_ + c] = f2bf(s * (1.f / TOPK_));
}

// ---------------------------------------------------------------------------
// Residual + RMSNorm, fused wo split-K reduce. Pp: [sp][514][2048]
// ---------------------------------------------------------------------------
__global__ __launch_bounds__(256) void resid_rmsnorm_kernel(const float* __restrict__ Pp,
                                                            int splits,
                                                            const float* __restrict__ x,
                                                            const int* __restrict__ sel_idx,
                                                            const float* __restrict__ nw,
                                                            short* __restrict__ HN) {
    int r = blockIdx.x;
    __shared__ float buf[D_];
    __shared__ float red4[4];
    const long spS = (long)ROWS_ALL * D_;
    const float* pr = Pp + (long)r * D_;
    const float* xr = nullptr;
    if (r < ROWS_SEL) {
        int b = r >> 8;
        int s = sel_idx[r];
        xr = x + ((long)b * S_ + s) * D_;
    }
    float ss = 0.f;
    for (int c = threadIdx.x; c < D_; c += 256) {
        float v = xr ? xr[c] : 0.f;
        for (int sp = 0; sp < splits; ++sp) v += pr[(long)sp * spS + c];
        buf[c] = v;
        ss += v * v;
    }
    float tot = block_sum_256(ss, red4);
    float scale = rsqrtf(tot / D_ + EPS_);
    for (int c = threadIdx.x; c < D_; c += 256)
        HN[(long)r * D_ + c] = f2bf(buf[c] * scale * nw[c]);
}

// ---------------------------------------------------------------------------
// reduce w1/w3 partials + silu-mul -> bf16. Gp: [mat][sp][514][8192], splits=2
// ---------------------------------------------------------------------------
__global__ __launch_bounds__(256) void reduce_silu_kernel(const float* __restrict__ Gp,
                                                          short* __restrict__ FF, long n) {
    long i = (long)blockIdx.x * 256 + threadIdx.x;
    if (i < n) {
        const long cz = (long)ROWS_ALL * HIDDEN_;
        float a = Gp[i] + Gp[cz + i];
        float g = Gp[2 * cz + i] + Gp[3 * cz + i];
        FF[i] = f2bf((a / (1.f + expf(-a))) * g);
    }
}

// ---------------------------------------------------------------------------
// reduce w2 partials (8) -> OUTR, float4 vectorized
// ---------------------------------------------------------------------------
__global__ __launch_bounds__(256) void w2_reduce_kernel(const float* __restrict__ Wp,
                                                        float* __restrict__ OUTR, long n4) {
    long i = (long)blockIdx.x * 256 + threadIdx.x;
    if (i < n4) {
        const long spS4 = (long)ROWS_ALL * D_ / 4;
        float4 s = ((const float4*)Wp)[i];
        for (int sp = 1; sp < 8; ++sp) {
            float4 v = ((const float4*)Wp)[(long)sp * spS4 + i];
            s.x += v.x; s.y += v.y; s.z += v.z; s.w += v.w;
        }
        ((float4*)OUTR)[i] = s;
    }
}

// ---------------------------------------------------------------------------
// Scatter rows to output
// ---------------------------------------------------------------------------
__global__ __launch_bounds__(256) void scatter_kernel(const float* __restrict__ OUTR,
                                                      const int* __restrict__ sel_pos,
                                                      float* __restrict__ out) {
    int blk = blockIdx.x;
    int b = blk >> 11;
    int p = sel_pos[blk];
    int row = (p >= 0) ? (b * TOPK_ + p) : (ROWS_SEL + b);
    const float* src = OUTR + (long)row * D_;
    float* dst = out + (long)blk * D_;
    for (int c = threadIdx.x; c < D_; c += 256) dst[c] = src[c];
}

// ---------------------------------------------------------------------------
extern "C" void kernel_launch(void* const* d_in, const int* in_sizes, int n_in,
                              void* d_out, int out_size, void* d_ws, size_t ws_size,
                              hipStream_t stream) {
    const float* x        = (const float*)d_in[0];
    const int*   startpos = (const int*)d_in[1];
    const float* freqs    = (const float*)d_in[2];
    const float* router_w = (const float*)d_in[3];
    const float* wq       = (const float*)d_in[4];
    const float* wk       = (const float*)d_in[5];
    const float* wv       = (const float*)d_in[6];
    const float* wo       = (const float*)d_in[7];
    const float* w1       = (const float*)d_in[8];
    const float* w2       = (const float*)d_in[9];
    const float* w3       = (const float*)d_in[10];
    const float* attn_w   = (const float*)d_in[11];
    const float* ffn_w    = (const float*)d_in[12];

    float* out     = (float*)d_out;
    float* tw_out  = out + (long)B_ * S_ * D_;
    float* idx_out = tw_out + (long)B_ * S_;

    char* ws = (char*)d_ws;
    auto alloc = [&](size_t bytes) -> void* {
        void* p = (void*)ws;
        ws += (bytes + 255) / 256 * 256;
        return p;
    };
    int*   sel_idx = (int*)alloc((size_t)B_ * TOPK_ * sizeof(int));
    int*   sel_pos = (int*)alloc((size_t)B_ * S_ * sizeof(int));
    short* XNbf = (short*)alloc((size_t)ROWS_SEL * D_ * sizeof(short));
    float* QKV  = (float*)alloc((size_t)3 * ROWS_SEL * D_ * sizeof(float));
    float* Qf = QKV;
    float* Kf = QKV + (size_t)ROWS_SEL * D_;
    float* Vf = QKV + (size_t)2 * ROWS_SEL * D_;
    float* SC   = (float*)alloc((size_t)B_ * H_ * TOPK_ * TOPK_ * sizeof(float));
    short* Obf  = (short*)alloc((size_t)ROWS_ALL * D_ * sizeof(short));
    short* HNbf = (short*)alloc((size_t)ROWS_ALL * D_ * sizeof(short));
    short* FFbf = (short*)alloc((size_t)ROWS_ALL * HIDDEN_ * sizeof(short));
    float* OUTR = (float*)alloc((size_t)ROWS_ALL * D_ * sizeof(float));
    // Split-K partial arena (reused across sequential phases): max user is
    // w1/w3 partials: 4 * 514 * 8192 f32 = 67.4 MB
    float* Gar  = (float*)alloc((size_t)4 * ROWS_ALL * HIDDEN_ * sizeof(float));
    // Transposed bf16 weights (all 7 resident simultaneously)
    const size_t W4M = (size_t)D_ * D_;
    const size_t W16M = (size_t)D_ * HIDDEN_;
    short* WT = (short*)alloc((4 * W4M + 3 * W16M) * sizeof(short));
    short* wqT = WT;
    short* wkT = wqT + W4M;
    short* wvT = wkT + W4M;
    short* woT = wvT + W4M;
    short* w1T = woT + W4M;
    short* w3T = w1T + W16M;
    short* w2T = w3T + W16M;

    const float inv_sqrt_hd = 0.08838834764831845f;

    // 0. All weight transposes in one launch
    {
        TransParams tp;
        tp.src[0] = wq; tp.src[1] = wk; tp.src[2] = wv; tp.src[3] = wo;
        tp.src[4] = w1; tp.src[5] = w3; tp.src[6] = w2;
        tp.dst[0] = wqT; tp.dst[1] = wkT; tp.dst[2] = wvT; tp.dst[3] = woT;
        tp.dst[4] = w1T; tp.dst[5] = w3T; tp.dst[6] = w2T;
        int Ks[7] = {D_, D_, D_, D_, D_, D_, HIDDEN_};
        int Ns[7] = {D_, D_, D_, D_, HIDDEN_, HIDDEN_, D_};
        int acc = 0;
        for (int i = 0; i < 7; ++i) {
            tp.K[i] = Ks[i]; tp.N[i] = Ns[i];
            tp.pref[i] = acc;
            acc += (Ns[i] / 64) * (Ks[i] / 64);
        }
        tp.pref[7] = acc;  // 16384
        transpose_all<<<acc, 256, 0, stream>>>(tp);
    }
    // 1. Router
    router_kernel<<<B_ * S_, 256, 0, stream>>>(x, router_w, tw_out);
    // 2. Top-k
    topk_kernel<<<B_, 1024, 0, stream>>>(tw_out, idx_out, sel_idx, sel_pos);
    // 3. Gather + RMSNorm -> bf16
    gather_rmsnorm_kernel<<<ROWS_SEL, 256, 0, stream>>>(x, sel_idx, attn_w, XNbf);
    // 4. QKV MFMA GEMM, split-K=4: partials [sp][mat][512][2048] in Gar
    {
        dim3 g(D_ / 128, ROWS_SEL / 128, 3 * 4);
        gemm_mfma<<<g, 256, 0, stream>>>(XNbf, wqT, wkT, wvT,
                                         Gar, (long)ROWS_SEL * D_, (long)3 * ROWS_SEL * D_,
                                         ROWS_SEL, D_, D_, D_ / 4, 4);
    }
    // 5. Reduce + rotary -> Qf,Kf,Vf
    qkv_finish<<<ROWS_SEL, 256, 0, stream>>>(Gar, freqs, sel_idx, startpos, Qf, Kf, Vf, 4);
    // 6. Scores = Q K^T / sqrt(HD)   (f32)
    {
        dim3 g(TOPK_ / 64, TOPK_ / 64, B_ * H_);
        gemm_tile<true, false><<<g, 256, 0, stream>>>(
            Qf, D_, (long)TOPK_ * D_, HD_,
            Kf, D_, (long)TOPK_ * D_, HD_,
            SC, TOPK_, (long)H_ * TOPK_ * TOPK_, (long)TOPK_ * TOPK_,
            TOPK_, TOPK_, HD_, H_, inv_sqrt_hd);
    }
    // 7. Softmax
    softmax_kernel<<<B_ * H_ * TOPK_, 256, 0, stream>>>(SC);
    // 8. O = P @ V -> bf16 Obf
    {
        dim3 g(HD_ / 64, TOPK_ / 64, B_ * H_);
        gemm_tile<false, true><<<g, 256, 0, stream>>>(
            SC, TOPK_, (long)H_ * TOPK_ * TOPK_, (long)TOPK_ * TOPK_,
            Vf, D_, (long)TOPK_ * D_, HD_,
            Obf, D_, (long)TOPK_ * D_, HD_,
            TOPK_, HD_, TOPK_, H_, 1.f);
    }
    // 9. vbar rows -> bf16
    {
        dim3 g(D_ / 256, B_, 1);
        vbar_kernel<<<g, 256, 0, stream>>>(Vf, Obf);
    }
    // 10. wo projection, split-K=8: partials [sp][514][2048] in Gar
    {
        dim3 g(D_ / 128, (ROWS_ALL + 127) / 128, 8);
        gemm_mfma<<<g, 256, 0, stream>>>(Obf, woT, woT, woT,
                                         Gar, 0, (long)ROWS_ALL * D_,
                                         ROWS_ALL, D_, D_, D_ / 8, 8);
    }
    // 11. Residual + RMSNorm (fused wo-reduce) -> bf16
    resid_rmsnorm_kernel<<<ROWS_ALL, 256, 0, stream>>>(Gar, 8, x, sel_idx, ffn_w, HNbf);
    // 12. w1/w3 up-projections, split-K=2: partials [mat][sp][514][8192]
    {
        dim3 g(HIDDEN_ / 128, (ROWS_ALL + 127) / 128, 2 * 2);
        gemm_mfma<<<g, 256, 0, stream>>>(HNbf, w1T, w3T, w3T,
                                         Gar, (long)2 * ROWS_ALL * HIDDEN_, (long)ROWS_ALL * HIDDEN_,
                                         ROWS_ALL, HIDDEN_, D_, D_ / 2, 2);
    }
    // 13. reduce + silu-mul -> bf16
    {
        long n = (long)ROWS_ALL * HIDDEN_;
        reduce_silu_kernel<<<(unsigned)((n + 255) / 256), 256, 0, stream>>>(Gar, FFbf, n);
    }
    // 14. w2 down-projection, split-K=8: partials [sp][514][2048]
    {
        dim3 g(D_ / 128, (ROWS_ALL + 127) / 128, 8);
        gemm_mfma<<<g, 256, 0, stream>>>(FFbf, w2T, w2T, w2T,
                                         Gar, 0, (long)ROWS_ALL * D_,
                                         ROWS_ALL, D_, HIDDEN_, HIDDEN_ / 8, 8);
    }
    // 15. reduce w2 partials
    {
        long n4 = (long)ROWS_ALL * D_ / 4;
        w2_reduce_kernel<<<(unsigned)((n4 + 255) / 256), 256, 0, stream>>>(Gar, OUTR, n4);
    }
    // 16. Scatter
    scatter_kernel<<<B_ * S_, 256, 0, stream>>>(OUTR, sel_pos, out);
}

// Round 4
// 572.248 us; speedup vs baseline: 5.2470x; 1.1190x over previous
//
#include <hip/hip_runtime.h>
#include <hip/hip_bf16.h>
#include <math.h>

// Problem constants
#define B_ 2
#define S_ 2048
#define D_ 2048
#define H_ 16
#define HD_ 128
#define TOPK_ 256
#define HIDDEN_ 8192
#define EPS_ 1e-6f

constexpr int ROWS_SEL = B_ * TOPK_;      // 512 selected rows (both batches)
constexpr int ROWS_ALL = ROWS_SEL + B_;   // +2 "unselected representative" rows

typedef __attribute__((ext_vector_type(8))) short bf16x8;
typedef __attribute__((ext_vector_type(4))) float f32x4;

__device__ __forceinline__ short f2bf(float f) {
    __hip_bfloat16 h = __float2bfloat16(f);
    return *reinterpret_cast<short*>(&h);
}

__device__ __forceinline__ float bf2f(short s) {
    union { unsigned u; float f; } c;
    c.u = ((unsigned)(unsigned short)s) << 16;
    return c.f;
}

__device__ __forceinline__ void gll16(const void* g, void* l) {
    __builtin_amdgcn_global_load_lds(
        (const __attribute__((address_space(1))) unsigned int*)g,
        (__attribute__((address_space(3))) unsigned int*)l, 16, 0, 0);
}

// ---------------------------------------------------------------------------
// Block reduction helpers
// ---------------------------------------------------------------------------
__device__ __forceinline__ float block_sum_256(float v, float* red4) {
    for (int o = 32; o; o >>= 1) v += __shfl_down(v, o);
    if ((threadIdx.x & 63) == 0) red4[threadIdx.x >> 6] = v;
    __syncthreads();
    float t = red4[0] + red4[1] + red4[2] + red4[3];
    __syncthreads();
    return t;
}

__device__ __forceinline__ float block_max_256(float v, float* red4) {
    for (int o = 32; o; o >>= 1) v = fmaxf(v, __shfl_down(v, o));
    if ((threadIdx.x & 63) == 0) red4[threadIdx.x >> 6] = v;
    __syncthreads();
    float t = fmaxf(fmaxf(red4[0], red4[1]), fmaxf(red4[2], red4[3]));
    __syncthreads();
    return t;
}

// ---------------------------------------------------------------------------
// 1. Router (exact f32), float4-vectorized
// ---------------------------------------------------------------------------
__global__ __launch_bounds__(256) void router_kernel(const float* __restrict__ x,
                                                     const float* __restrict__ rw,
                                                     float* __restrict__ tw) {
    int token = blockIdx.x;
    const float4* xr = (const float4*)(x + (long)token * D_);
    const float4* r4 = (const float4*)rw;
    float s = 0.f;
    for (int c = threadIdx.x; c < D_ / 4; c += 256) {
        float4 a = xr[c], b = r4[c];
        s += a.x * b.x + a.y * b.y + a.z * b.z + a.w * b.w;
    }
    __shared__ float red4[4];
    float tot = block_sum_256(s, red4);
    if (threadIdx.x == 0) tw[token] = tot;
}

// ---------------------------------------------------------------------------
// 2. Top-k per batch (bitonic, value desc / index asc)
// ---------------------------------------------------------------------------
__global__ __launch_bounds__(1024) void topk_kernel(const float* __restrict__ tw,
                                                    float* __restrict__ idx_out,
                                                    int* __restrict__ sel_idx,
                                                    int* __restrict__ sel_pos) {
    int b = blockIdx.x;
    __shared__ float v[S_];
    __shared__ int id[S_];
    int t = threadIdx.x;
    for (int i = t; i < S_; i += 1024) {
        v[i] = tw[b * S_ + i];
        id[i] = i;
        sel_pos[b * S_ + i] = -1;
    }
    __syncthreads();
    for (int k = 2; k <= S_; k <<= 1) {
        for (int j = k >> 1; j > 0; j >>= 1) {
            for (int i = t; i < S_; i += 1024) {
                int ixj = i ^ j;
                if (ixj > i) {
                    float va = v[i], vb = v[ixj];
                    int ia = id[i], ib = id[ixj];
                    bool before = (va > vb) || (va == vb && ia < ib);
                    bool dir = ((i & k) == 0);
                    if (dir != before) {
                        v[i] = vb; v[ixj] = va;
                        id[i] = ib; id[ixj] = ia;
                    }
                }
            }
            __syncthreads();
        }
    }
    if (t < TOPK_) {
        idx_out[b * TOPK_ + t] = (float)id[t];
        sel_idx[b * TOPK_ + t] = id[t];
        sel_pos[b * S_ + id[t]] = t;
    }
}

// ---------------------------------------------------------------------------
// 3. Gather + RMSNorm -> bf16
// ---------------------------------------------------------------------------
__global__ __launch_bounds__(256) void gather_rmsnorm_kernel(const float* __restrict__ x,
                                                             const int* __restrict__ sel_idx,
                                                             const float* __restrict__ nw,
                                                             short* __restrict__ XN) {
    int r = blockIdx.x;
    int b = r >> 8;
    int s = sel_idx[r];
    const float* xr = x + ((long)b * S_ + s) * D_;
    __shared__ float buf[D_];
    __shared__ float red4[4];
    float ss = 0.f;
    for (int c = threadIdx.x; c < D_; c += 256) {
        float vv = xr[c];
        buf[c] = vv;
        ss += vv * vv;
    }
    float tot = block_sum_256(ss, red4);
    float scale = rsqrtf(tot / D_ + EPS_);
    for (int c = threadIdx.x; c < D_; c += 256)
        XN[(long)r * D_ + c] = f2bf(buf[c] * scale * nw[c]);
}

// ---------------------------------------------------------------------------
// MFMA GEMM with f32 weights consumed directly (no pre-transpose).
// C(f32 partial) = A(bf16 MxKtot) @ B(f32 Ktot x N, row-major), split-K.
// grid.z = zmat*splits + sp. Partial -> Cb + zmat*czStride + sp*spStride.
// A staged bf16 via global_load_lds; B staged f32 [32][128] via
// global_load_lds (per-lane global addrs), fragments gathered k-wise with
// ds_read_b32 and converted to bf16 in registers.
// ---------------------------------------------------------------------------
__global__ __launch_bounds__(256) void gemm_mfma_w(
    const short* __restrict__ A,
    const float* __restrict__ B0, const float* __restrict__ B1, const float* __restrict__ B2,
    float* __restrict__ Cb, long czStride, long spStride,
    int M, int N, int Ktot, int K_per, int splits) {
    __shared__ short As[128 * 32];   // 8 KB  [row][k] bf16
    __shared__ float Bs[32 * 128];   // 16 KB [k][n] f32
    int z = blockIdx.z;
    int zmat = z / splits, sp = z % splits;
    const float* Bm = (zmat == 0) ? B0 : (zmat == 1) ? B1 : B2;
    float* C = Cb + (long)zmat * czStride + (long)sp * spStride;
    int kbase = sp * K_per;
    int row0 = blockIdx.y * 128, col0 = blockIdx.x * 128;
    int t = threadIdx.x;
    int lane = t & 63, w = t >> 6;
    int l16 = lane & 15, quad = lane >> 4;
    int wr = (w >> 1) * 64, wc = (w & 1) * 64;
    int arr = t >> 2, ach = (t & 3) * 8;     // A staging: row arr(+64), k-chunk ach
    int bkr = t >> 5, bnc = (t & 31) * 4;    // B staging: k-row bkr(+8*rd), n-col bnc
    f32x4 acc[4][4] = {};
    for (int k0 = kbase; k0 < kbase + K_per; k0 += 32) {
        __syncthreads();
        #pragma unroll
        for (int rd = 0; rd < 2; ++rd) {
            int ar = row0 + arr + rd * 64; ar = (ar < M) ? ar : (M - 1);
            gll16(A + (size_t)ar * Ktot + k0 + ach, (char*)As + rd * 4096 + t * 16);
        }
        #pragma unroll
        for (int rd = 0; rd < 4; ++rd) {
            int kr = k0 + rd * 8 + bkr;
            gll16(Bm + (size_t)kr * N + col0 + bnc, (char*)Bs + rd * 4096 + t * 16);
        }
        __syncthreads();
        bf16x8 af[4], bf[4];
        #pragma unroll
        for (int i = 0; i < 4; ++i)
            af[i] = *(const bf16x8*)(As + (wr + i * 16 + l16) * 32 + quad * 8);
        #pragma unroll
        for (int j = 0; j < 4; ++j) {
            int n = wc + j * 16 + l16;
            union { short s[8]; bf16x8 v; } ub;
            #pragma unroll
            for (int jj = 0; jj < 8; ++jj)
                ub.s[jj] = f2bf(Bs[(quad * 8 + jj) * 128 + n]);
            bf[j] = ub.v;
        }
        #pragma unroll
        for (int i = 0; i < 4; ++i)
            #pragma unroll
            for (int j = 0; j < 4; ++j)
                acc[i][j] = __builtin_amdgcn_mfma_f32_16x16x32_bf16(af[i], bf[j], acc[i][j], 0, 0, 0);
    }
    #pragma unroll
    for (int i = 0; i < 4; ++i) {
        #pragma unroll
        for (int r = 0; r < 4; ++r) {
            int row = row0 + wr + i * 16 + quad * 4 + r;
            if (row < M) {
                #pragma unroll
                for (int j = 0; j < 4; ++j)
                    C[(size_t)row * N + col0 + wc + j * 16 + l16] = acc[i][j][r];
            }
        }
    }
}

// ---------------------------------------------------------------------------
// Batched bf16 MFMA GEMM for attention: C = A @ B^T per z.
// A: rows M, k-contig, row stride lda; B: rows N, k-contig, row stride ldb.
// Per-z offsets: (z/inner)*sXo + (z%inner)*sXi. OBF: write bf16 else f32.
// ---------------------------------------------------------------------------
template <bool OBF>
__global__ __launch_bounds__(256) void gemm_mfma_attn(
    const short* __restrict__ A, long sAo, long sAi, int lda,
    const short* __restrict__ Bm, long sBo, long sBi, int ldb,
    void* __restrict__ Cv, long sCo, long sCi, int ldc,
    int M, int N, int K, int inner) {
    __shared__ short smem[2 * 128 * 32];
    short* As = smem;
    short* Bs = smem + 128 * 32;
    int z = blockIdx.z;
    int zo = z / inner, zi = z % inner;
    const short* Ab = A + (long)zo * sAo + (long)zi * sAi;
    const short* Bb = Bm + (long)zo * sBo + (long)zi * sBi;
    long cbase = (long)zo * sCo + (long)zi * sCi;
    int row0 = blockIdx.y * 128, col0 = blockIdx.x * 128;
    int t = threadIdx.x;
    int lane = t & 63, w = t >> 6;
    int l16 = lane & 15, quad = lane >> 4;
    int wr = (w >> 1) * 64, wc = (w & 1) * 64;
    int rr = t >> 2, ch = (t & 3) * 8;
    f32x4 acc[4][4] = {};
    for (int k0 = 0; k0 < K; k0 += 32) {
        __syncthreads();
        #pragma unroll
        for (int rd = 0; rd < 2; ++rd) {
            int r = rr + rd * 64;
            int ar = row0 + r; ar = (ar < M) ? ar : (M - 1);
            gll16(Ab + (size_t)ar * lda + k0 + ch, (char*)As + rd * 4096 + t * 16);
            gll16(Bb + (size_t)(col0 + r) * ldb + k0 + ch, (char*)Bs + rd * 4096 + t * 16);
        }
        __syncthreads();
        bf16x8 af[4], bfr[4];
        #pragma unroll
        for (int i = 0; i < 4; ++i)
            af[i] = *(const bf16x8*)(As + (wr + i * 16 + l16) * 32 + quad * 8);
        #pragma unroll
        for (int j = 0; j < 4; ++j)
            bfr[j] = *(const bf16x8*)(Bs + (wc + j * 16 + l16) * 32 + quad * 8);
        #pragma unroll
        for (int i = 0; i < 4; ++i)
            #pragma unroll
            for (int j = 0; j < 4; ++j)
                acc[i][j] = __builtin_amdgcn_mfma_f32_16x16x32_bf16(af[i], bfr[j], acc[i][j], 0, 0, 0);
    }
    #pragma unroll
    for (int i = 0; i < 4; ++i) {
        #pragma unroll
        for (int r = 0; r < 4; ++r) {
            int row = row0 + wr + i * 16 + quad * 4 + r;
            if (row < M) {
                #pragma unroll
                for (int j = 0; j < 4; ++j) {
                    long idx = cbase + (size_t)row * ldc + col0 + wc + j * 16 + l16;
                    if (OBF) ((short*)Cv)[idx] = f2bf(acc[i][j][r]);
                    else     ((float*)Cv)[idx] = acc[i][j][r];
                }
            }
        }
    }
}

// ---------------------------------------------------------------------------
// QKV finish: reduce split-K partials + rotary -> bf16 Qbf (pre-scaled), Kbf, Vbf
// Cp layout: [sp][mat(q,k,v)][512][2048]
// ---------------------------------------------------------------------------
__global__ __launch_bounds__(256) void qkv_finish(
    const float* __restrict__ Cp, const float* __restrict__ fc,
    const int* __restrict__ sel_idx, const int* __restrict__ sp0,
    short* __restrict__ Qbf, short* __restrict__ Kbf, short* __restrict__ Vbf,
    int splits) {
    int r = blockIdx.x;
    int s = sel_idx[r];
    int pos = sp0[0] + s;
    const float* f = fc + (long)pos * HD_;
    const long matS = (long)ROWS_SEL * D_;
    const long spS = 3 * matS;
    const float* qp = Cp + (long)r * D_;
    const float* kp = qp + matS;
    const float* vp = qp + 2 * matS;
    const float qscale = 0.08838834764831845f;  // 1/sqrt(128)
    for (int p = threadIdx.x; p < (D_ / 2); p += 256) {
        int h = p >> 6, d2 = p & 63;
        int e0 = h * HD_ + d2 * 2;
        float q0 = 0.f, q1 = 0.f, k0 = 0.f, k1 = 0.f, v0 = 0.f, v1 = 0.f;
        for (int sp = 0; sp < splits; ++sp) {
            long off = (long)sp * spS;
            q0 += qp[off + e0]; q1 += qp[off + e0 + 1];
            k0 += kp[off + e0]; k1 += kp[off + e0 + 1];
            v0 += vp[off + e0]; v1 += vp[off + e0 + 1];
        }
        float c = f[d2 * 2], sn = f[d2 * 2 + 1];
        Qbf[(long)r * D_ + e0]     = f2bf((q0 * c - q1 * sn) * qscale);
        Qbf[(long)r * D_ + e0 + 1] = f2bf((q0 * sn + q1 * c) * qscale);
        Kbf[(long)r * D_ + e0]     = f2bf(k0 * c - k1 * sn);
        Kbf[(long)r * D_ + e0 + 1] = f2bf(k0 * sn + k1 * c);
        Vbf[(long)r * D_ + e0]     = f2bf(v0);
        Vbf[(long)r * D_ + e0 + 1] = f2bf(v1);
    }
}

// ---------------------------------------------------------------------------
// V transpose per (b,h): Vbf[b*256+key][h*128+d] -> VT[z][d][key] (bf16)
// grid: (keytiles=4, dimtiles=2, z=32)
// ---------------------------------------------------------------------------
__global__ __launch_bounds__(256) void vt_kernel(const short* __restrict__ Vbf,
                                                 short* __restrict__ VT) {
    int z = blockIdx.z;
    int b = z >> 4, h = z & 15;
    int key0 = blockIdx.x * 64, d0 = blockIdx.y * 64;
    __shared__ short L[64][72];
    int t = threadIdx.x;
    int kr = t >> 3, dc = (t & 7) * 8;
    #pragma unroll
    for (int rr = 0; rr < 2; ++rr) {
        int key = kr + rr * 32;
        union { short s[8]; int4 v; } u;
        u.v = *(const int4*)&Vbf[(size_t)(b * 256 + key0 + key) * D_ + h * 128 + d0 + dc];
        #pragma unroll
        for (int j = 0; j < 8; ++j) L[key][dc + j] = u.s[j];
    }
    __syncthreads();
    int dr = t >> 3, kc = (t & 7) * 8;
    #pragma unroll
    for (int rr = 0; rr < 2; ++rr) {
        int d = dr + rr * 32;
        union { short s[8]; int4 v; } u;
        #pragma unroll
        for (int j = 0; j < 8; ++j) u.s[j] = L[kc + j][d];
        *(int4*)&VT[((size_t)z * 128 + d0 + d) * 256 + key0 + kc] = u.v;
    }
}

// ---------------------------------------------------------------------------
// Softmax over each 256-score row -> bf16 probs
// ---------------------------------------------------------------------------
__global__ __launch_bounds__(256) void softmax_kernel(const float* __restrict__ SC,
                                                      short* __restrict__ Pbf) {
    long row = blockIdx.x;
    const float* p = SC + row * 256;
    int t = threadIdx.x;
    float v = p[t];
    __shared__ float red4[4];
    float m = block_max_256(v, red4);
    float e = expf(v - m);
    float s = block_sum_256(e, red4);
    Pbf[row * 256 + t] = f2bf(e / s);
}

// ---------------------------------------------------------------------------
// vbar: mean of selected V rows per batch -> Obf rows 512+b (bf16)
// ---------------------------------------------------------------------------
__global__ __launch_bounds__(256) void vbar_kernel(const short* __restrict__ Vbf,
                                                   short* __restrict__ Obf) {
    int b = blockIdx.y;
    int c = blockIdx.x * 256 + threadIdx.x;
    float s = 0.f;
    for (int i = 0; i < TOPK_; ++i) s += bf2f(Vbf[((long)b * TOPK_ + i) * D_ + c]);
    Obf[(long)(ROWS_SEL + b) * D_ + c] = f2bf(s * (1.f / TOPK_));
}

// ---------------------------------------------------------------------------
// Residual + RMSNorm, fused wo split-K reduce. Pp: [sp][514][2048]
// ---------------------------------------------------------------------------
__global__ __launch_bounds__(256) void resid_rmsnorm_kernel(const float* __restrict__ Pp,
                                                            int splits,
                                                            const float* __restrict__ x,
                                                            const int* __restrict__ sel_idx,
                                                            const float* __restrict__ nw,
                                                            short* __restrict__ HN) {
    int r = blockIdx.x;
    __shared__ float buf[D_];
    __shared__ float red4[4];
    const long spS = (long)ROWS_ALL * D_;
    const float* pr = Pp + (long)r * D_;
    const float* xr = nullptr;
    if (r < ROWS_SEL) {
        int b = r >> 8;
        int s = sel_idx[r];
        xr = x + ((long)b * S_ + s) * D_;
    }
    float ss = 0.f;
    for (int c = threadIdx.x; c < D_; c += 256) {
        float v = xr ? xr[c] : 0.f;
        for (int sp = 0; sp < splits; ++sp) v += pr[(long)sp * spS + c];
        buf[c] = v;
        ss += v * v;
    }
    float tot = block_sum_256(ss, red4);
    float scale = rsqrtf(tot / D_ + EPS_);
    for (int c = threadIdx.x; c < D_; c += 256)
        HN[(long)r * D_ + c] = f2bf(buf[c] * scale * nw[c]);
}

// ---------------------------------------------------------------------------
// reduce w1/w3 partials + silu-mul -> bf16. Gp: [mat][sp][514][8192], splits=2
// ---------------------------------------------------------------------------
__global__ __launch_bounds__(256) void reduce_silu_kernel(const float* __restrict__ Gp,
                                                          short* __restrict__ FF, long n) {
    long i = (long)blockIdx.x * 256 + threadIdx.x;
    if (i < n) {
        const long cz = (long)ROWS_ALL * HIDDEN_;
        float a = Gp[i] + Gp[cz + i];
        float g = Gp[2 * cz + i] + Gp[3 * cz + i];
        FF[i] = f2bf((a / (1.f + expf(-a))) * g);
    }
}

// ---------------------------------------------------------------------------
// reduce w2 partials (8) -> OUTR, float4 vectorized
// ---------------------------------------------------------------------------
__global__ __launch_bounds__(256) void w2_reduce_kernel(const float* __restrict__ Wp,
                                                        float* __restrict__ OUTR, long n4) {
    long i = (long)blockIdx.x * 256 + threadIdx.x;
    if (i < n4) {
        const long spS4 = (long)ROWS_ALL * D_ / 4;
        float4 s = ((const float4*)Wp)[i];
        for (int sp = 1; sp < 8; ++sp) {
            float4 v = ((const float4*)Wp)[(long)sp * spS4 + i];
            s.x += v.x; s.y += v.y; s.z += v.z; s.w += v.w;
        }
        ((float4*)OUTR)[i] = s;
    }
}

// ---------------------------------------------------------------------------
// Scatter rows to output (float4)
// ---------------------------------------------------------------------------
__global__ __launch_bounds__(256) void scatter_kernel(const float* __restrict__ OUTR,
                                                      const int* __restrict__ sel_pos,
                                                      float* __restrict__ out) {
    int blk = blockIdx.x;
    int b = blk >> 11;
    int p = sel_pos[blk];
    int row = (p >= 0) ? (b * TOPK_ + p) : (ROWS_SEL + b);
    const float4* src = (const float4*)(OUTR + (long)row * D_);
    float4* dst = (float4*)(out + (long)blk * D_);
    for (int c = threadIdx.x; c < D_ / 4; c += 256) dst[c] = src[c];
}

// ---------------------------------------------------------------------------
extern "C" void kernel_launch(void* const* d_in, const int* in_sizes, int n_in,
                              void* d_out, int out_size, void* d_ws, size_t ws_size,
                              hipStream_t stream) {
    const float* x        = (const float*)d_in[0];
    const int*   startpos = (const int*)d_in[1];
    const float* freqs    = (const float*)d_in[2];
    const float* router_w = (const float*)d_in[3];
    const float* wq       = (const float*)d_in[4];
    const float* wk       = (const float*)d_in[5];
    const float* wv       = (const float*)d_in[6];
    const float* wo       = (const float*)d_in[7];
    const float* w1       = (const float*)d_in[8];
    const float* w2       = (const float*)d_in[9];
    const float* w3       = (const float*)d_in[10];
    const float* attn_w   = (const float*)d_in[11];
    const float* ffn_w    = (const float*)d_in[12];

    float* out     = (float*)d_out;
    float* tw_out  = out + (long)B_ * S_ * D_;
    float* idx_out = tw_out + (long)B_ * S_;

    char* ws = (char*)d_ws;
    auto alloc = [&](size_t bytes) -> void* {
        void* p = (void*)ws;
        ws += (bytes + 255) / 256 * 256;
        return p;
    };
    int*   sel_idx = (int*)alloc((size_t)B_ * TOPK_ * sizeof(int));
    int*   sel_pos = (int*)alloc((size_t)B_ * S_ * sizeof(int));
    short* XNbf = (short*)alloc((size_t)ROWS_SEL * D_ * sizeof(short));
    short* Qbf  = (short*)alloc((size_t)ROWS_SEL * D_ * sizeof(short));
    short* Kbf  = (short*)alloc((size_t)ROWS_SEL * D_ * sizeof(short));
    short* Vbf  = (short*)alloc((size_t)ROWS_SEL * D_ * sizeof(short));
    short* VT   = (short*)alloc((size_t)B_ * H_ * HD_ * TOPK_ * sizeof(short));
    float* SC   = (float*)alloc((size_t)B_ * H_ * TOPK_ * TOPK_ * sizeof(float));
    short* Pbf  = (short*)alloc((size_t)B_ * H_ * TOPK_ * TOPK_ * sizeof(short));
    short* Obf  = (short*)alloc((size_t)ROWS_ALL * D_ * sizeof(short));
    short* HNbf = (short*)alloc((size_t)ROWS_ALL * D_ * sizeof(short));
    short* FFbf = (short*)alloc((size_t)ROWS_ALL * HIDDEN_ * sizeof(short));
    float* OUTR = (float*)alloc((size_t)ROWS_ALL * D_ * sizeof(float));
    // Split-K partial arena: max = w1/w3 partials 4 * 514 * 8192 f32 = 67.4 MB
    float* Gar  = (float*)alloc((size_t)4 * ROWS_ALL * HIDDEN_ * sizeof(float));

    // 1. Router
    router_kernel<<<B_ * S_, 256, 0, stream>>>(x, router_w, tw_out);
    // 2. Top-k
    topk_kernel<<<B_, 1024, 0, stream>>>(tw_out, idx_out, sel_idx, sel_pos);
    // 3. Gather + RMSNorm -> bf16
    gather_rmsnorm_kernel<<<ROWS_SEL, 256, 0, stream>>>(x, sel_idx, attn_w, XNbf);
    // 4. QKV GEMM (f32 weights direct), split-K=4: partials [sp][mat][512][2048]
    {
        dim3 g(D_ / 128, ROWS_SEL / 128, 3 * 4);
        gemm_mfma_w<<<g, 256, 0, stream>>>(XNbf, wq, wk, wv,
                                           Gar, (long)ROWS_SEL * D_, (long)3 * ROWS_SEL * D_,
                                           ROWS_SEL, D_, D_, D_ / 4, 4);
    }
    // 5. Reduce + rotary -> bf16 Q (pre-scaled), K, V
    qkv_finish<<<ROWS_SEL, 256, 0, stream>>>(Gar, freqs, sel_idx, startpos, Qbf, Kbf, Vbf, 4);
    // 6. V transpose per (b,h)
    {
        dim3 g(4, 2, B_ * H_);
        vt_kernel<<<g, 256, 0, stream>>>(Vbf, VT);
    }
    // 7. Scores = (Q/sqrt(HD)) K^T  (bf16 MFMA, f32 out)
    {
        dim3 g(2, 2, B_ * H_);
        gemm_mfma_attn<false><<<g, 256, 0, stream>>>(
            Qbf, (long)TOPK_ * D_, HD_, D_,
            Kbf, (long)TOPK_ * D_, HD_, D_,
            SC, (long)H_ * TOPK_ * TOPK_, (long)TOPK_ * TOPK_, TOPK_,
            TOPK_, TOPK_, HD_, H_);
    }
    // 8. Softmax -> bf16 probs
    softmax_kernel<<<B_ * H_ * TOPK_, 256, 0, stream>>>(SC, Pbf);
    // 9. O = P @ V (bf16 MFMA via VT), bf16 out into Obf (head-strided)
    {
        dim3 g(1, 2, B_ * H_);
        gemm_mfma_attn<true><<<g, 256, 0, stream>>>(
            Pbf, (long)H_ * TOPK_ * TOPK_, (long)TOPK_ * TOPK_, TOPK_,
            VT, (long)H_ * HD_ * TOPK_, (long)HD_ * TOPK_, TOPK_,
            Obf, (long)TOPK_ * D_, HD_, D_,
            TOPK_, HD_, TOPK_, H_);
    }
    // 10. vbar rows -> bf16
    {
        dim3 g(D_ / 256, B_, 1);
        vbar_kernel<<<g, 256, 0, stream>>>(Vbf, Obf);
    }
    // 11. wo projection, split-K=8: partials [sp][514][2048]
    {
        dim3 g(D_ / 128, (ROWS_ALL + 127) / 128, 8);
        gemm_mfma_w<<<g, 256, 0, stream>>>(Obf, wo, wo, wo,
                                           Gar, 0, (long)ROWS_ALL * D_,
                                           ROWS_ALL, D_, D_, D_ / 8, 8);
    }
    // 12. Residual + RMSNorm (fused wo-reduce) -> bf16
    resid_rmsnorm_kernel<<<ROWS_ALL, 256, 0, stream>>>(Gar, 8, x, sel_idx, ffn_w, HNbf);
    // 13. w1/w3 up-projections, split-K=2: partials [mat][sp][514][8192]
    {
        dim3 g(HIDDEN_ / 128, (ROWS_ALL + 127) / 128, 2 * 2);
        gemm_mfma_w<<<g, 256, 0, stream>>>(HNbf, w1, w3, w3,
                                           Gar, (long)2 * ROWS_ALL * HIDDEN_, (long)ROWS_ALL * HIDDEN_,
                                           ROWS_ALL, HIDDEN_, D_, D_ / 2, 2);
    }
    // 14. reduce + silu-mul -> bf16
    {
        long n = (long)ROWS_ALL * HIDDEN_;
        reduce_silu_kernel<<<(unsigned)((n + 255) / 256), 256, 0, stream>>>(Gar, FFbf, n);
    }
    // 15. w2 down-projection, split-K=8: partials [sp][514][2048]
    {
        dim3 g(D_ / 128, (ROWS_ALL + 127) / 128, 8);
        gemm_mfma_w<<<g, 256, 0, stream>>>(FFbf, w2, w2, w2,
                                           Gar, 0, (long)ROWS_ALL * D_,
                                           ROWS_ALL, D_, HIDDEN_, HIDDEN_ / 8, 8);
    }
    // 16. reduce w2 partials
    {
        long n4 = (long)ROWS_ALL * D_ / 4;
        w2_reduce_kernel<<<(unsigned)((n4 + 255) / 256), 256, 0, stream>>>(Gar, OUTR, n4);
    }
    // 17. Scatter
    scatter_kernel<<<B_ * S_, 256, 0, stream>>>(OUTR, sel_pos, out);
}